// Round 1
// baseline (3634.208 us; speedup 1.0000x reference)
//
#include <hip/hip_runtime.h>
#include <math.h>

#define N_NODES 50000
#define F_IN    512
#define HDIM    256
#define L_OUT   52
#define E_EDGES 1600000

// ---------------------------------------------------------------- CSR build

__global__ void k_count(const int* __restrict__ dst, int* __restrict__ cnt, int E) {
    int i = blockIdx.x * blockDim.x + threadIdx.x;
    int stride = gridDim.x * blockDim.x;
    for (; i < E; i += stride) atomicAdd(&cnt[dst[i]], 1);
}

__global__ void k_dinv(const int* __restrict__ cnt, float* __restrict__ dinv, int n) {
    int i = blockIdx.x * blockDim.x + threadIdx.x;
    if (i < n) dinv[i] = rsqrtf((float)(cnt[i] + 1));  // +1 self-loop
}

// single-block exclusive scan (N=50000, 196 chunks of 256)
__global__ void k_scan(const int* __restrict__ cnt, int* __restrict__ rowptr, int n) {
    __shared__ int s[256];
    __shared__ int carry;
    int tid = threadIdx.x;
    if (tid == 0) carry = 0;
    __syncthreads();
    for (int base = 0; base < n; base += 256) {
        int idx = base + tid;
        int v = (idx < n) ? cnt[idx] : 0;
        s[tid] = v;
        __syncthreads();
        for (int off = 1; off < 256; off <<= 1) {
            int t = (tid >= off) ? s[tid - off] : 0;
            __syncthreads();
            s[tid] += t;
            __syncthreads();
        }
        int incl = s[tid];
        int c = carry;
        if (idx < n) rowptr[idx] = c + incl - v;
        __syncthreads();
        if (tid == 255) carry = c + s[255];
        __syncthreads();
    }
    if (tid == 0) rowptr[n] = carry;
}

__global__ void k_fill(const int* __restrict__ src, const int* __restrict__ dst,
                       const int* __restrict__ rowptr, int* __restrict__ cursor,
                       int* __restrict__ col, int E) {
    int i = blockIdx.x * blockDim.x + threadIdx.x;
    int stride = gridDim.x * blockDim.x;
    for (; i < E; i += stride) {
        int d = dst[i];
        int p = atomicAdd(&cursor[d], 1);
        col[rowptr[d] + p] = src[i];
    }
}

// ------------------------------------------------- aggregation (wave/node)

__global__ void k_agg(const float* __restrict__ g, const int* __restrict__ rowptr,
                      const int* __restrict__ col, const float* __restrict__ dinv,
                      const float* __restrict__ bias, float* __restrict__ out,
                      int n, int do_relu) {
    int gtid = blockIdx.x * blockDim.x + threadIdx.x;
    int wid = gtid >> 6;
    int lane = threadIdx.x & 63;
    if (wid >= n) return;
    float di = dinv[wid];
    const float4* grow = (const float4*)(g + (size_t)wid * HDIM);
    float4 acc = grow[lane];
    float w0 = di * di;
    acc.x *= w0; acc.y *= w0; acc.z *= w0; acc.w *= w0;
    int r0 = rowptr[wid], r1 = rowptr[wid + 1];
    for (int e = r0; e < r1; ++e) {
        int j = col[e];
        float wj = dinv[j] * di;
        float4 v = ((const float4*)(g + (size_t)j * HDIM))[lane];
        acc.x = fmaf(v.x, wj, acc.x);
        acc.y = fmaf(v.y, wj, acc.y);
        acc.z = fmaf(v.z, wj, acc.z);
        acc.w = fmaf(v.w, wj, acc.w);
    }
    float4 bb = ((const float4*)bias)[lane];
    float4 o;
    o.x = acc.x + bb.x; o.y = acc.y + bb.y; o.z = acc.z + bb.z; o.w = acc.w + bb.w;
    if (do_relu) {
        o.x = fmaxf(o.x, 0.f); o.y = fmaxf(o.y, 0.f);
        o.z = fmaxf(o.z, 0.f); o.w = fmaxf(o.w, 0.f);
    }
    ((float4*)(out + (size_t)wid * HDIM))[lane] = o;
}

// ---------------------------------------------------------- fp32 GEMM 64x64
// EPI: 0 = plain (no bias), 1 = bias+relu, 2 = bias+sigmoid

template <int EPI>
__global__ __launch_bounds__(256) void k_gemm(const float* __restrict__ A,
                                              const float* __restrict__ B,
                                              const float* __restrict__ bias,
                                              float* __restrict__ C,
                                              int M, int K, int Nc) {
    __shared__ float As[16][68];  // [k][m], padded: 2-way max on scalar writes
    __shared__ float Bs[16][64];  // [k][n]

    int tid = threadIdx.x;
    int tx = tid & 15;        // n-group
    int ty = tid >> 4;        // m-group
    int mb = blockIdx.y * 64;
    int nb = blockIdx.x * 64;

    int arow = tid >> 2;            // 0..63
    int akk  = (tid & 3) << 2;      // 0,4,8,12
    int brow = tid >> 4;            // 0..15
    int bn4  = (tid & 15) << 2;     // 0..60

    float4 acc[4];
#pragma unroll
    for (int i = 0; i < 4; i++) acc[i] = make_float4(0.f, 0.f, 0.f, 0.f);

    for (int k0 = 0; k0 < K; k0 += 16) {
        // A tile: rows mb..mb+63, cols k0..k0+15
        float4 av = make_float4(0.f, 0.f, 0.f, 0.f);
        if (mb + arow < M)
            av = *(const float4*)&A[(size_t)(mb + arow) * K + k0 + akk];
        As[akk + 0][arow] = av.x;
        As[akk + 1][arow] = av.y;
        As[akk + 2][arow] = av.z;
        As[akk + 3][arow] = av.w;
        // B tile: rows k0..k0+15, cols nb..nb+63
        float4 bv = make_float4(0.f, 0.f, 0.f, 0.f);
        int bcol = nb + bn4;
        if (bcol + 3 < Nc) {
            bv = *(const float4*)&B[(size_t)(k0 + brow) * Nc + bcol];
        } else {
            float tmp[4] = {0.f, 0.f, 0.f, 0.f};
            for (int t = 0; t < 4; t++)
                if (bcol + t < Nc) tmp[t] = B[(size_t)(k0 + brow) * Nc + bcol + t];
            bv = make_float4(tmp[0], tmp[1], tmp[2], tmp[3]);
        }
        *(float4*)&Bs[brow][bn4] = bv;
        __syncthreads();

#pragma unroll
        for (int k = 0; k < 16; k++) {
            float4 a4 = *(const float4*)&As[k][ty * 4];
            float4 b4 = *(const float4*)&Bs[k][tx * 4];
            float a_[4] = {a4.x, a4.y, a4.z, a4.w};
#pragma unroll
            for (int i = 0; i < 4; i++) {
                acc[i].x = fmaf(a_[i], b4.x, acc[i].x);
                acc[i].y = fmaf(a_[i], b4.y, acc[i].y);
                acc[i].z = fmaf(a_[i], b4.z, acc[i].z);
                acc[i].w = fmaf(a_[i], b4.w, acc[i].w);
            }
        }
        __syncthreads();
    }

#pragma unroll
    for (int i = 0; i < 4; i++) {
        int m = mb + ty * 4 + i;
        if (m >= M) continue;
        float vals[4] = {acc[i].x, acc[i].y, acc[i].z, acc[i].w};
#pragma unroll
        for (int j = 0; j < 4; j++) {
            int n = nb + tx * 4 + j;
            if (n >= Nc) continue;
            float v = vals[j];
            if (EPI >= 1) v += bias[n];
            if (EPI == 1) v = fmaxf(v, 0.f);
            if (EPI == 2) v = 1.f / (1.f + expf(-v));
            C[(size_t)m * Nc + n] = v;
        }
    }
}

// ------------------------------------------------------------- gate fusion

__global__ void k_gate(const float* __restrict__ h1, const float* __restrict__ h2,
                       const float* __restrict__ w1, const float* __restrict__ w1b,
                       const float* __restrict__ w2, const float* __restrict__ w2b,
                       float* __restrict__ m, int n) {
    int gtid = blockIdx.x * blockDim.x + threadIdx.x;
    int wid = gtid >> 6;
    int lane = threadIdx.x & 63;
    if (wid >= n) return;
    float4 a = ((const float4*)(h1 + (size_t)wid * HDIM))[lane];
    float4 b = ((const float4*)(h2 + (size_t)wid * HDIM))[lane];
    float4 wa = ((const float4*)w1)[lane];
    float4 wb = ((const float4*)w2)[lane];
    float d1 = a.x * wa.x + a.y * wa.y + a.z * wa.z + a.w * wa.w;
    float d2 = b.x * wb.x + b.y * wb.y + b.z * wb.z + b.w * wb.w;
    for (int off = 32; off > 0; off >>= 1) {
        d1 += __shfl_xor(d1, off);
        d2 += __shfl_xor(d2, off);
    }
    float f1 = 1.f / (1.f + expf(-(d1 + w1b[0])));
    float f2 = 1.f / (1.f + expf(-(d2 + w2b[0])));
    float f = f1 / (f1 + f2);
    float4 o;
    o.x = f * a.x + (1.f - f) * b.x;
    o.y = f * a.y + (1.f - f) * b.y;
    o.z = f * a.z + (1.f - f) * b.z;
    o.w = f * a.w + (1.f - f) * b.w;
    ((float4*)(m + (size_t)wid * HDIM))[lane] = o;
}

// ------------------------------------------------------------------ launch

extern "C" void kernel_launch(void* const* d_in, const int* in_sizes, int n_in,
                              void* d_out, int out_size, void* d_ws, size_t ws_size,
                              hipStream_t stream) {
    (void)n_in; (void)out_size; (void)ws_size;
    const int N = N_NODES, E = E_EDGES;

    // input order = setup_inputs dict order; defensively detect signature order
    const float* x1; const float* x2; const int* ei1; const int* ei2;
    if (in_sizes[1] == 2 * E) {  // x_1, edge_index_1, x_2, edge_index_2
        x1 = (const float*)d_in[0]; ei1 = (const int*)d_in[1];
        x2 = (const float*)d_in[2]; ei2 = (const int*)d_in[3];
    } else {                     // x_1, x_2, edge_index_1, edge_index_2
        x1 = (const float*)d_in[0]; x2 = (const float*)d_in[1];
        ei1 = (const int*)d_in[2]; ei2 = (const int*)d_in[3];
    }
    const float* W[2][4]; const float* Bv[2][4];
    int idx = 4;
    for (int br = 0; br < 2; br++)
        for (int l = 0; l < 4; l++) {
            W[br][l] = (const float*)d_in[idx++];
            Bv[br][l] = (const float*)d_in[idx++];
        }
    const float* w1W  = (const float*)d_in[20];
    const float* w1b  = (const float*)d_in[21];
    const float* w2W  = (const float*)d_in[22];
    const float* w2b  = (const float*)d_in[23];
    const float* finW = (const float*)d_in[24];
    const float* finb = (const float*)d_in[25];
    const float* outW = (const float*)d_in[26];
    const float* outb = (const float*)d_in[27];
    float* out = (float*)d_out;

    // workspace layout
    size_t off = 0;
    auto alloc = [&](size_t bytes) {
        void* p = (char*)d_ws + off;
        off = (off + bytes + 255) & ~(size_t)255;
        return p;
    };
    float* g    = (float*)alloc((size_t)N * HDIM * 4);
    float* h1   = (float*)alloc((size_t)N * HDIM * 4);
    float* h2   = (float*)alloc((size_t)N * HDIM * 4);
    int* col    = (int*)alloc((size_t)E * 4);
    int* rowptr = (int*)alloc((size_t)(N + 1) * 4);
    int* cnt    = (int*)alloc((size_t)N * 4);
    int* cursor = (int*)alloc((size_t)N * 4);
    float* dinv = (float*)alloc((size_t)N * 4);

    const int BLK = 256;
    int nwaves_grid = (N * 64 + BLK - 1) / BLK;   // wave-per-node kernels
    dim3 gemm_grid_h((HDIM + 63) / 64, (N + 63) / 64);
    dim3 gemm_grid_o((L_OUT + 63) / 64, (N + 63) / 64);

    for (int br = 0; br < 2; br++) {
        const int* src = br ? ei2 : ei1;
        const int* dst = src + E;
        const float* x = br ? x2 : x1;
        float* hb = br ? h2 : h1;

        hipMemsetAsync(cnt, 0, (size_t)N * 4, stream);
        hipMemsetAsync(cursor, 0, (size_t)N * 4, stream);
        k_count<<<2048, BLK, 0, stream>>>(dst, cnt, E);
        k_scan<<<1, BLK, 0, stream>>>(cnt, rowptr, N);
        k_dinv<<<(N + BLK - 1) / BLK, BLK, 0, stream>>>(cnt, dinv, N);
        k_fill<<<2048, BLK, 0, stream>>>(src, dst, rowptr, cursor, col, E);

        // layer 1: K=512
        k_gemm<0><<<gemm_grid_h, BLK, 0, stream>>>(x, W[br][0], nullptr, g, N, F_IN, HDIM);
        k_agg<<<nwaves_grid, BLK, 0, stream>>>(g, rowptr, col, dinv, Bv[br][0], hb, N, 1);
        // layers 2,3: K=256, relu
        for (int l = 1; l <= 2; l++) {
            k_gemm<0><<<gemm_grid_h, BLK, 0, stream>>>(hb, W[br][l], nullptr, g, N, HDIM, HDIM);
            k_agg<<<nwaves_grid, BLK, 0, stream>>>(g, rowptr, col, dinv, Bv[br][l], hb, N, 1);
        }
        // layer e: no relu
        k_gemm<0><<<gemm_grid_h, BLK, 0, stream>>>(hb, W[br][3], nullptr, g, N, HDIM, HDIM);
        k_agg<<<nwaves_grid, BLK, 0, stream>>>(g, rowptr, col, dinv, Bv[br][3], hb, N, 0);
    }

    // gate: m (into g)
    k_gate<<<nwaves_grid, BLK, 0, stream>>>(h1, h2, w1W, w1b, w2W, w2b, g, N);
    // fin: relu(m @ finW + finb) -> h1
    k_gemm<1><<<gemm_grid_h, BLK, 0, stream>>>(g, finW, finb, h1, N, HDIM, HDIM);
    // out: sigmoid(t @ outW + outb) -> d_out
    k_gemm<2><<<gemm_grid_o, BLK, 0, stream>>>(h1, outW, outb, out, N, HDIM, L_OUT);
}

// Round 2
// 2865.588 us; speedup vs baseline: 1.2682x; 1.2682x over previous
//
#include <hip/hip_runtime.h>
#include <math.h>

#define N_NODES 50000
#define F_IN    512
#define HDIM    256
#define L_OUT   52
#define E_EDGES 1600000

typedef short short8 __attribute__((ext_vector_type(8)));
typedef float f32x4 __attribute__((ext_vector_type(4)));

__device__ __forceinline__ float bf2f(unsigned short u) {
    unsigned int x = ((unsigned int)u) << 16;
    return __builtin_bit_cast(float, x);
}
__device__ __forceinline__ unsigned short f2bf(float f) {
    unsigned int u = __builtin_bit_cast(unsigned int, f);
    return (unsigned short)((u + 0x7fffu + ((u >> 16) & 1u)) >> 16);
}
__device__ __forceinline__ void gload16(const unsigned short* g, unsigned short* l) {
    __builtin_amdgcn_global_load_lds(
        (const __attribute__((address_space(1))) unsigned int*)(g),
        (__attribute__((address_space(3))) unsigned int*)(l), 16, 0, 0);
}

// ---------------------------------------------------------------- CSR build

__global__ void k_count(const int* __restrict__ dst, int* __restrict__ cnt, int E) {
    int i = blockIdx.x * blockDim.x + threadIdx.x;
    int stride = gridDim.x * blockDim.x;
    for (; i < E; i += stride) atomicAdd(&cnt[dst[i]], 1);
}

__global__ void k_dinv(const int* __restrict__ cnt, float* __restrict__ dinv, int n) {
    int i = blockIdx.x * blockDim.x + threadIdx.x;
    if (i < n) dinv[i] = rsqrtf((float)(cnt[i] + 1));  // +1 self-loop
}

__global__ void k_scan(const int* __restrict__ cnt, int* __restrict__ rowptr, int n) {
    __shared__ int s[256];
    __shared__ int carry;
    int tid = threadIdx.x;
    if (tid == 0) carry = 0;
    __syncthreads();
    for (int base = 0; base < n; base += 256) {
        int idx = base + tid;
        int v = (idx < n) ? cnt[idx] : 0;
        s[tid] = v;
        __syncthreads();
        for (int off = 1; off < 256; off <<= 1) {
            int t = (tid >= off) ? s[tid - off] : 0;
            __syncthreads();
            s[tid] += t;
            __syncthreads();
        }
        int incl = s[tid];
        int c = carry;
        if (idx < n) rowptr[idx] = c + incl - v;
        __syncthreads();
        if (tid == 255) carry = c + s[255];
        __syncthreads();
    }
    if (tid == 0) rowptr[n] = carry;
}

__global__ void k_fill(const int* __restrict__ src, const int* __restrict__ dst,
                       const int* __restrict__ rowptr, int* __restrict__ cursor,
                       int* __restrict__ col, int E) {
    int i = blockIdx.x * blockDim.x + threadIdx.x;
    int stride = gridDim.x * blockDim.x;
    for (; i < E; i += stride) {
        int d = dst[i];
        int p = atomicAdd(&cursor[d], 1);
        col[rowptr[d] + p] = src[i];
    }
}

// ------------------------------------------------------------- conversions

__global__ void k_f2b(const float* __restrict__ in, unsigned short* __restrict__ out, int n4) {
    int i = blockIdx.x * blockDim.x + threadIdx.x;
    int stride = gridDim.x * blockDim.x;
    for (; i < n4; i += stride) {
        float4 v = ((const float4*)in)[i];
        ushort4 o;
        o.x = f2bf(v.x); o.y = f2bf(v.y); o.z = f2bf(v.z); o.w = f2bf(v.w);
        ((ushort4*)out)[i] = o;
    }
}

// fp32 [K][N] -> bf16 [N][K] (transpose)
__global__ void k_f2b_t(const float* __restrict__ in, unsigned short* __restrict__ out,
                        int K, int N) {
    int idx = blockIdx.x * blockDim.x + threadIdx.x;
    if (idx < K * N) {
        int k = idx / N, n = idx % N;
        out[(size_t)n * K + k] = f2bf(in[idx]);
    }
}

// ------------------------------------------- aggregation (wave/node, bf16)

__global__ void k_agg(const unsigned short* __restrict__ g, const int* __restrict__ rowptr,
                      const int* __restrict__ col, const float* __restrict__ dinv,
                      const float* __restrict__ bias, unsigned short* __restrict__ out,
                      int n, int do_relu) {
    int gtid = blockIdx.x * blockDim.x + threadIdx.x;
    int wid = gtid >> 6;
    int lane = threadIdx.x & 63;
    if (wid >= n) return;
    float di = dinv[wid];
    ushort4 v0 = ((const ushort4*)(g + (size_t)wid * HDIM))[lane];
    float w0 = di * di;
    float a0 = bf2f(v0.x) * w0, a1 = bf2f(v0.y) * w0, a2 = bf2f(v0.z) * w0, a3 = bf2f(v0.w) * w0;
    int r0 = rowptr[wid], r1 = rowptr[wid + 1];
    for (int e = r0; e < r1; ++e) {
        int j = col[e];
        float wj = dinv[j] * di;
        ushort4 v = ((const ushort4*)(g + (size_t)j * HDIM))[lane];
        a0 = fmaf(bf2f(v.x), wj, a0);
        a1 = fmaf(bf2f(v.y), wj, a1);
        a2 = fmaf(bf2f(v.z), wj, a2);
        a3 = fmaf(bf2f(v.w), wj, a3);
    }
    float4 bb = ((const float4*)bias)[lane];
    a0 += bb.x; a1 += bb.y; a2 += bb.z; a3 += bb.w;
    if (do_relu) {
        a0 = fmaxf(a0, 0.f); a1 = fmaxf(a1, 0.f);
        a2 = fmaxf(a2, 0.f); a3 = fmaxf(a3, 0.f);
    }
    ushort4 o;
    o.x = f2bf(a0); o.y = f2bf(a1); o.z = f2bf(a2); o.w = f2bf(a3);
    ((ushort4*)(out + (size_t)wid * HDIM))[lane] = o;
}

// --------------------------------------------------- bf16 MFMA GEMM 128x128
// A: [M][K] bf16 row-major.  Bt: [N][K] bf16 (pre-transposed weights).
// EPI 0: raw -> bf16 C (stride Nc).  EPI 1: bias+relu -> bf16.
// EPI 2: bias+sigmoid -> fp32 C, col < Nc guard (Nc may be < padded tile).

template <int EPI>
__global__ __launch_bounds__(256) void k_gemm(const unsigned short* __restrict__ A,
                                              const unsigned short* __restrict__ Bt,
                                              const float* __restrict__ bias,
                                              void* __restrict__ Cout,
                                              int M, int K, int Nc) {
    __shared__ __align__(16) unsigned short As[128 * 32];
    __shared__ __align__(16) unsigned short Bs[128 * 32];
    int tid = threadIdx.x;
    int wid = tid >> 6, lane = tid & 63;
    int wr = wid >> 1, wc = wid & 1;
    int mb = blockIdx.y * 128, nb = blockIdx.x * 128;

    // staging: thread t -> 16B at LDS offset t*16 (row r=t>>2, slot t&3);
    // source k-segment pre-swizzled so swizzled reads see linear data (T2/m173)
    int sr = tid >> 2;
    int ssl = (tid & 3) ^ ((sr >> 1) & 3);   // same for row sr and sr+64
    int ar0 = mb + sr;      if (ar0 > M - 1) ar0 = M - 1;
    int ar1 = mb + sr + 64; if (ar1 > M - 1) ar1 = M - 1;
    const unsigned short* gA0 = A + (size_t)ar0 * K + ssl * 8;
    const unsigned short* gA1 = A + (size_t)ar1 * K + ssl * 8;
    const unsigned short* gB0 = Bt + (size_t)(nb + sr) * K + ssl * 8;
    const unsigned short* gB1 = Bt + (size_t)(nb + sr + 64) * K + ssl * 8;
    unsigned short* ldsA = As + tid * 8;     // *8 shorts = 16B
    unsigned short* ldsB = Bs + tid * 8;

    f32x4 acc[4][4];
#pragma unroll
    for (int m = 0; m < 4; m++)
#pragma unroll
        for (int n = 0; n < 4; n++) acc[m][n] = (f32x4){0.f, 0.f, 0.f, 0.f};

    int l15 = lane & 15, ks = lane >> 4;

    for (int k0 = 0; k0 < K; k0 += 32) {
        gload16(gA0 + k0, ldsA);
        gload16(gA1 + k0, ldsA + 2048);
        gload16(gB0 + k0, ldsB);
        gload16(gB1 + k0, ldsB + 2048);
        __syncthreads();   // compiler emits vmcnt(0) drain before barrier

        short8 af[4], bfr[4];
#pragma unroll
        for (int m = 0; m < 4; m++) {
            int row = wr * 64 + m * 16 + l15;
            int slot = ks ^ ((row >> 1) & 3);
            af[m] = *(const short8*)((const char*)As + row * 64 + slot * 16);
        }
#pragma unroll
        for (int n = 0; n < 4; n++) {
            int row = wc * 64 + n * 16 + l15;
            int slot = ks ^ ((row >> 1) & 3);
            bfr[n] = *(const short8*)((const char*)Bs + row * 64 + slot * 16);
        }
#pragma unroll
        for (int m = 0; m < 4; m++)
#pragma unroll
            for (int n = 0; n < 4; n++)
                acc[m][n] = __builtin_amdgcn_mfma_f32_16x16x32_bf16(af[m], bfr[n], acc[m][n], 0, 0, 0);
        __syncthreads();
    }

    int lq = lane >> 4;
#pragma unroll
    for (int m = 0; m < 4; m++) {
#pragma unroll
        for (int n = 0; n < 4; n++) {
            int gcol = nb + wc * 64 + n * 16 + l15;
#pragma unroll
            for (int r = 0; r < 4; r++) {
                int grow = mb + wr * 64 + m * 16 + lq * 4 + r;
                if (grow >= M) continue;
                float v = acc[m][n][r];
                if (EPI == 0) {
                    ((unsigned short*)Cout)[(size_t)grow * Nc + gcol] = f2bf(v);
                } else if (EPI == 1) {
                    v += bias[gcol];
                    v = fmaxf(v, 0.f);
                    ((unsigned short*)Cout)[(size_t)grow * Nc + gcol] = f2bf(v);
                } else {
                    if (gcol < Nc) {
                        v += bias[gcol];
                        v = 1.f / (1.f + expf(-v));
                        ((float*)Cout)[(size_t)grow * Nc + gcol] = v;
                    }
                }
            }
        }
    }
}

// ------------------------------------------------------------- gate fusion

__global__ void k_gate(const unsigned short* __restrict__ h1, const unsigned short* __restrict__ h2,
                       const float* __restrict__ w1, const float* __restrict__ w1b,
                       const float* __restrict__ w2, const float* __restrict__ w2b,
                       unsigned short* __restrict__ m, int n) {
    int gtid = blockIdx.x * blockDim.x + threadIdx.x;
    int wid = gtid >> 6;
    int lane = threadIdx.x & 63;
    if (wid >= n) return;
    ushort4 av = ((const ushort4*)(h1 + (size_t)wid * HDIM))[lane];
    ushort4 bv = ((const ushort4*)(h2 + (size_t)wid * HDIM))[lane];
    float4 wa = ((const float4*)w1)[lane];
    float4 wb = ((const float4*)w2)[lane];
    float a0 = bf2f(av.x), a1 = bf2f(av.y), a2 = bf2f(av.z), a3 = bf2f(av.w);
    float b0 = bf2f(bv.x), b1 = bf2f(bv.y), b2 = bf2f(bv.z), b3 = bf2f(bv.w);
    float d1 = a0 * wa.x + a1 * wa.y + a2 * wa.z + a3 * wa.w;
    float d2 = b0 * wb.x + b1 * wb.y + b2 * wb.z + b3 * wb.w;
    for (int off = 32; off > 0; off >>= 1) {
        d1 += __shfl_xor(d1, off);
        d2 += __shfl_xor(d2, off);
    }
    float f1 = 1.f / (1.f + expf(-(d1 + w1b[0])));
    float f2 = 1.f / (1.f + expf(-(d2 + w2b[0])));
    float f = f1 / (f1 + f2);
    ushort4 o;
    o.x = f2bf(f * a0 + (1.f - f) * b0);
    o.y = f2bf(f * a1 + (1.f - f) * b1);
    o.z = f2bf(f * a2 + (1.f - f) * b2);
    o.w = f2bf(f * a3 + (1.f - f) * b3);
    ((ushort4*)(m + (size_t)wid * HDIM))[lane] = o;
}

// ------------------------------------------------------------------ launch

extern "C" void kernel_launch(void* const* d_in, const int* in_sizes, int n_in,
                              void* d_out, int out_size, void* d_ws, size_t ws_size,
                              hipStream_t stream) {
    (void)n_in; (void)out_size; (void)ws_size;
    const int N = N_NODES, E = E_EDGES;

    const float* x1; const float* x2; const int* ei1; const int* ei2;
    if (in_sizes[1] == 2 * E) {
        x1 = (const float*)d_in[0]; ei1 = (const int*)d_in[1];
        x2 = (const float*)d_in[2]; ei2 = (const int*)d_in[3];
    } else {
        x1 = (const float*)d_in[0]; x2 = (const float*)d_in[1];
        ei1 = (const int*)d_in[2]; ei2 = (const int*)d_in[3];
    }
    const float* W[2][4]; const float* Bv[2][4];
    int idx = 4;
    for (int br = 0; br < 2; br++)
        for (int l = 0; l < 4; l++) {
            W[br][l] = (const float*)d_in[idx++];
            Bv[br][l] = (const float*)d_in[idx++];
        }
    const float* w1W  = (const float*)d_in[20];
    const float* w1b  = (const float*)d_in[21];
    const float* w2W  = (const float*)d_in[22];
    const float* w2b  = (const float*)d_in[23];
    const float* finW = (const float*)d_in[24];
    const float* finb = (const float*)d_in[25];
    const float* outW = (const float*)d_in[26];
    const float* outb = (const float*)d_in[27];
    float* out = (float*)d_out;

    size_t off = 0;
    auto alloc = [&](size_t bytes) {
        void* p = (char*)d_ws + off;
        off = (off + bytes + 255) & ~(size_t)255;
        return p;
    };
    unsigned short* xb  = (unsigned short*)alloc((size_t)N * F_IN * 2);  // 51.2MB, also fin-out t
    unsigned short* gb  = (unsigned short*)alloc((size_t)N * HDIM * 2);  // GEMM out / gate out m
    unsigned short* h1b = (unsigned short*)alloc((size_t)N * HDIM * 2);
    unsigned short* h2b = (unsigned short*)alloc((size_t)N * HDIM * 2);
    unsigned short* Wt[2][4];
    Wt[0][0] = (unsigned short*)alloc((size_t)HDIM * F_IN * 2);
    for (int l = 1; l < 4; l++) Wt[0][l] = (unsigned short*)alloc((size_t)HDIM * HDIM * 2);
    Wt[1][0] = (unsigned short*)alloc((size_t)HDIM * F_IN * 2);
    for (int l = 1; l < 4; l++) Wt[1][l] = (unsigned short*)alloc((size_t)HDIM * HDIM * 2);
    unsigned short* finWt = (unsigned short*)alloc((size_t)HDIM * HDIM * 2);
    unsigned short* outWt = (unsigned short*)alloc((size_t)128 * HDIM * 2);  // padded 128 rows
    int* col    = (int*)alloc((size_t)E * 4);
    int* rowptr = (int*)alloc((size_t)(N + 1) * 4);
    int* cnt    = (int*)alloc((size_t)N * 4);
    int* cursor = (int*)alloc((size_t)N * 4);
    float* dinv = (float*)alloc((size_t)N * 4);

    const int BLK = 256;
    int nwaves_grid = (N * 64 + BLK - 1) / BLK;
    int mtiles = (N + 127) / 128;
    dim3 grid_h(HDIM / 128, mtiles);   // (2, 391)
    dim3 grid_o(1, mtiles);            // out GEMM, padded N=128

    // weight conversions (transpose to [N][K] bf16)
    hipMemsetAsync(outWt, 0, (size_t)128 * HDIM * 2, stream);
    for (int br = 0; br < 2; br++) {
        k_f2b_t<<<(F_IN * HDIM + 255) / 256, BLK, 0, stream>>>(W[br][0], Wt[br][0], F_IN, HDIM);
        for (int l = 1; l < 4; l++)
            k_f2b_t<<<(HDIM * HDIM + 255) / 256, BLK, 0, stream>>>(W[br][l], Wt[br][l], HDIM, HDIM);
    }
    k_f2b_t<<<(HDIM * HDIM + 255) / 256, BLK, 0, stream>>>(finW, finWt, HDIM, HDIM);
    k_f2b_t<<<(HDIM * L_OUT + 255) / 256, BLK, 0, stream>>>(outW, outWt, HDIM, L_OUT);

    for (int br = 0; br < 2; br++) {
        const int* src = br ? ei2 : ei1;
        const int* dst = src + E;
        const float* x = br ? x2 : x1;
        unsigned short* hb = br ? h2b : h1b;

        hipMemsetAsync(cnt, 0, (size_t)N * 4, stream);
        hipMemsetAsync(cursor, 0, (size_t)N * 4, stream);
        k_count<<<2048, BLK, 0, stream>>>(dst, cnt, E);
        k_scan<<<1, BLK, 0, stream>>>(cnt, rowptr, N);
        k_dinv<<<(N + BLK - 1) / BLK, BLK, 0, stream>>>(cnt, dinv, N);
        k_fill<<<2048, BLK, 0, stream>>>(src, dst, rowptr, cursor, col, E);

        // convert x to bf16 (xb reused across branches; stream-sequential)
        k_f2b<<<2048, BLK, 0, stream>>>(x, xb, N * F_IN / 4);

        // layer 1: K=512
        k_gemm<0><<<grid_h, BLK, 0, stream>>>(xb, Wt[br][0], nullptr, gb, N, F_IN, HDIM);
        k_agg<<<nwaves_grid, BLK, 0, stream>>>(gb, rowptr, col, dinv, Bv[br][0], hb, N, 1);
        // layers 2,3: K=256, relu
        for (int l = 1; l <= 2; l++) {
            k_gemm<0><<<grid_h, BLK, 0, stream>>>(hb, Wt[br][l], nullptr, gb, N, HDIM, HDIM);
            k_agg<<<nwaves_grid, BLK, 0, stream>>>(gb, rowptr, col, dinv, Bv[br][l], hb, N, 1);
        }
        // layer e: no relu
        k_gemm<0><<<grid_h, BLK, 0, stream>>>(hb, Wt[br][3], nullptr, gb, N, HDIM, HDIM);
        k_agg<<<nwaves_grid, BLK, 0, stream>>>(gb, rowptr, col, dinv, Bv[br][3], hb, N, 0);
    }

    // gate -> m (gb)
    k_gate<<<nwaves_grid, BLK, 0, stream>>>(h1b, h2b, w1W, w1b, w2W, w2b, gb, N);
    // fin: relu(m @ finW + finb) -> t (xb)
    k_gemm<1><<<grid_h, BLK, 0, stream>>>(gb, finWt, finb, xb, N, HDIM, HDIM);
    // out: sigmoid(t @ outW + outb) -> d_out  (padded tile, col<52 guard)
    k_gemm<2><<<grid_o, BLK, 0, stream>>>(xb, outWt, outb, out, N, HDIM, L_OUT);
}

// Round 3
// 2046.157 us; speedup vs baseline: 1.7761x; 1.4005x over previous
//
#include <hip/hip_runtime.h>
#include <math.h>

#define N_NODES 50000
#define F_IN    512
#define HDIM    256
#define L_OUT   52
#define E_EDGES 1600000

typedef short short8 __attribute__((ext_vector_type(8)));
typedef float f32x4 __attribute__((ext_vector_type(4)));

__device__ __forceinline__ float bf2f(unsigned short u) {
    unsigned int x = ((unsigned int)u) << 16;
    return __builtin_bit_cast(float, x);
}
__device__ __forceinline__ unsigned short f2bf(float f) {
    unsigned int u = __builtin_bit_cast(unsigned int, f);
    return (unsigned short)((u + 0x7fffu + ((u >> 16) & 1u)) >> 16);
}
__device__ __forceinline__ void gload16(const unsigned short* g, unsigned short* l) {
    __builtin_amdgcn_global_load_lds(
        (const __attribute__((address_space(1))) unsigned int*)(g),
        (__attribute__((address_space(3))) unsigned int*)(l), 16, 0, 0);
}

// ---------------------------------------------------------------- CSR build

__global__ void k_count(const int* __restrict__ dst, int* __restrict__ cnt, int E) {
    int i = blockIdx.x * blockDim.x + threadIdx.x;
    int stride = gridDim.x * blockDim.x;
    for (; i < E; i += stride) atomicAdd(&cnt[dst[i]], 1);
}

__global__ void k_dinv(const int* __restrict__ cnt, float* __restrict__ dinv, int n) {
    int i = blockIdx.x * blockDim.x + threadIdx.x;
    if (i < n) dinv[i] = rsqrtf((float)(cnt[i] + 1));  // +1 self-loop
}

__global__ void k_scan(const int* __restrict__ cnt, int* __restrict__ rowptr, int n) {
    __shared__ int s[256];
    __shared__ int carry;
    int tid = threadIdx.x;
    if (tid == 0) carry = 0;
    __syncthreads();
    for (int base = 0; base < n; base += 256) {
        int idx = base + tid;
        int v = (idx < n) ? cnt[idx] : 0;
        s[tid] = v;
        __syncthreads();
        for (int off = 1; off < 256; off <<= 1) {
            int t = (tid >= off) ? s[tid - off] : 0;
            __syncthreads();
            s[tid] += t;
            __syncthreads();
        }
        int incl = s[tid];
        int c = carry;
        if (idx < n) rowptr[idx] = c + incl - v;
        __syncthreads();
        if (tid == 255) carry = c + s[255];
        __syncthreads();
    }
    if (tid == 0) rowptr[n] = carry;
}

// fill CSR cols + per-edge weight wgt = dinv[src]*dinv[dst]
__global__ void k_fill(const int* __restrict__ src, const int* __restrict__ dst,
                       const int* __restrict__ rowptr, int* __restrict__ cursor,
                       const float* __restrict__ dinv,
                       int* __restrict__ col, float* __restrict__ wgt, int E) {
    int i = blockIdx.x * blockDim.x + threadIdx.x;
    int stride = gridDim.x * blockDim.x;
    for (; i < E; i += stride) {
        int s = src[i], d = dst[i];
        int p = atomicAdd(&cursor[d], 1);
        int pos = rowptr[d] + p;
        col[pos] = s;
        wgt[pos] = dinv[s] * dinv[d];
    }
}

// ------------------------------------------------------------- conversions

__global__ void k_f2b(const float* __restrict__ in, unsigned short* __restrict__ out, int n4) {
    int i = blockIdx.x * blockDim.x + threadIdx.x;
    int stride = gridDim.x * blockDim.x;
    for (; i < n4; i += stride) {
        float4 v = ((const float4*)in)[i];
        ushort4 o;
        o.x = f2bf(v.x); o.y = f2bf(v.y); o.z = f2bf(v.z); o.w = f2bf(v.w);
        ((ushort4*)out)[i] = o;
    }
}

// fp32 [K][N] -> bf16 [N][K] (transpose)
__global__ void k_f2b_t(const float* __restrict__ in, unsigned short* __restrict__ out,
                        int K, int N) {
    int idx = blockIdx.x * blockDim.x + threadIdx.x;
    if (idx < K * N) {
        int k = idx / N, n = idx % N;
        out[(size_t)n * K + k] = f2bf(in[idx]);
    }
}

// ---------------------- aggregation (wave/node, bf16, 8-deep MLP unroll)

__global__ void k_agg(const unsigned short* __restrict__ g, const int* __restrict__ rowptr,
                      const int* __restrict__ col, const float* __restrict__ wgt,
                      const float* __restrict__ dinv,
                      const float* __restrict__ bias, unsigned short* __restrict__ out,
                      int n, int do_relu) {
    int gtid = blockIdx.x * blockDim.x + threadIdx.x;
    int wid = gtid >> 6;
    int lane = threadIdx.x & 63;
    if (wid >= n) return;
    float di = dinv[wid];
    ushort4 v0 = ((const ushort4*)(g + (size_t)wid * HDIM))[lane];
    float w0 = di * di;  // self-loop weight
    float a0 = bf2f(v0.x) * w0, a1 = bf2f(v0.y) * w0, a2 = bf2f(v0.z) * w0, a3 = bf2f(v0.w) * w0;
    int r0 = rowptr[wid], r1 = rowptr[wid + 1];

    int e = r0;
    for (; e + 8 <= r1; e += 8) {
        int j[8]; float w[8]; ushort4 v[8];
#pragma unroll
        for (int t = 0; t < 8; t++) { j[t] = col[e + t]; w[t] = wgt[e + t]; }
#pragma unroll
        for (int t = 0; t < 8; t++)
            v[t] = ((const ushort4*)(g + (size_t)j[t] * HDIM))[lane];
#pragma unroll
        for (int t = 0; t < 8; t++) {
            a0 = fmaf(bf2f(v[t].x), w[t], a0);
            a1 = fmaf(bf2f(v[t].y), w[t], a1);
            a2 = fmaf(bf2f(v[t].z), w[t], a2);
            a3 = fmaf(bf2f(v[t].w), w[t], a3);
        }
    }
    {   // remainder, still load-then-use
        int j[8]; float w[8]; ushort4 v[8];
        int m = r1 - e;
#pragma unroll
        for (int t = 0; t < 8; t++) {
            int idx = (t < m) ? e + t : r0;  // dummy safe index
            j[t] = col[idx]; w[t] = (t < m) ? wgt[idx] : 0.f;
        }
#pragma unroll
        for (int t = 0; t < 8; t++)
            v[t] = ((const ushort4*)(g + (size_t)j[t] * HDIM))[lane];
#pragma unroll
        for (int t = 0; t < 8; t++) {
            a0 = fmaf(bf2f(v[t].x), w[t], a0);
            a1 = fmaf(bf2f(v[t].y), w[t], a1);
            a2 = fmaf(bf2f(v[t].z), w[t], a2);
            a3 = fmaf(bf2f(v[t].w), w[t], a3);
        }
    }

    float4 bb = ((const float4*)bias)[lane];
    a0 += bb.x; a1 += bb.y; a2 += bb.z; a3 += bb.w;
    if (do_relu) {
        a0 = fmaxf(a0, 0.f); a1 = fmaxf(a1, 0.f);
        a2 = fmaxf(a2, 0.f); a3 = fmaxf(a3, 0.f);
    }
    ushort4 o;
    o.x = f2bf(a0); o.y = f2bf(a1); o.z = f2bf(a2); o.w = f2bf(a3);
    ((ushort4*)(out + (size_t)wid * HDIM))[lane] = o;
}

// --------------------------------------------------- bf16 MFMA GEMM 128x128

template <int EPI>
__global__ __launch_bounds__(256) void k_gemm(const unsigned short* __restrict__ A,
                                              const unsigned short* __restrict__ Bt,
                                              const float* __restrict__ bias,
                                              void* __restrict__ Cout,
                                              int M, int K, int Nc) {
    __shared__ __align__(16) unsigned short As[128 * 32];
    __shared__ __align__(16) unsigned short Bs[128 * 32];
    int tid = threadIdx.x;
    int wid = tid >> 6, lane = tid & 63;
    int wr = wid >> 1, wc = wid & 1;
    int mb = blockIdx.y * 128, nb = blockIdx.x * 128;

    int sr = tid >> 2;
    int ssl = (tid & 3) ^ ((sr >> 1) & 3);
    int ar0 = mb + sr;      if (ar0 > M - 1) ar0 = M - 1;
    int ar1 = mb + sr + 64; if (ar1 > M - 1) ar1 = M - 1;
    const unsigned short* gA0 = A + (size_t)ar0 * K + ssl * 8;
    const unsigned short* gA1 = A + (size_t)ar1 * K + ssl * 8;
    const unsigned short* gB0 = Bt + (size_t)(nb + sr) * K + ssl * 8;
    const unsigned short* gB1 = Bt + (size_t)(nb + sr + 64) * K + ssl * 8;
    unsigned short* ldsA = As + tid * 8;
    unsigned short* ldsB = Bs + tid * 8;

    f32x4 acc[4][4];
#pragma unroll
    for (int m = 0; m < 4; m++)
#pragma unroll
        for (int n = 0; n < 4; n++) acc[m][n] = (f32x4){0.f, 0.f, 0.f, 0.f};

    int l15 = lane & 15, ks = lane >> 4;

    for (int k0 = 0; k0 < K; k0 += 32) {
        gload16(gA0 + k0, ldsA);
        gload16(gA1 + k0, ldsA + 2048);
        gload16(gB0 + k0, ldsB);
        gload16(gB1 + k0, ldsB + 2048);
        __syncthreads();

        short8 af[4], bfr[4];
#pragma unroll
        for (int m = 0; m < 4; m++) {
            int row = wr * 64 + m * 16 + l15;
            int slot = ks ^ ((row >> 1) & 3);
            af[m] = *(const short8*)((const char*)As + row * 64 + slot * 16);
        }
#pragma unroll
        for (int n = 0; n < 4; n++) {
            int row = wc * 64 + n * 16 + l15;
            int slot = ks ^ ((row >> 1) & 3);
            bfr[n] = *(const short8*)((const char*)Bs + row * 64 + slot * 16);
        }
#pragma unroll
        for (int m = 0; m < 4; m++)
#pragma unroll
            for (int n = 0; n < 4; n++)
                acc[m][n] = __builtin_amdgcn_mfma_f32_16x16x32_bf16(af[m], bfr[n], acc[m][n], 0, 0, 0);
        __syncthreads();
    }

    int lq = lane >> 4;
#pragma unroll
    for (int m = 0; m < 4; m++) {
#pragma unroll
        for (int n = 0; n < 4; n++) {
            int gcol = nb + wc * 64 + n * 16 + l15;
#pragma unroll
            for (int r = 0; r < 4; r++) {
                int grow = mb + wr * 64 + m * 16 + lq * 4 + r;
                if (grow >= M) continue;
                float v = acc[m][n][r];
                if (EPI == 0) {
                    ((unsigned short*)Cout)[(size_t)grow * Nc + gcol] = f2bf(v);
                } else if (EPI == 1) {
                    v += bias[gcol];
                    v = fmaxf(v, 0.f);
                    ((unsigned short*)Cout)[(size_t)grow * Nc + gcol] = f2bf(v);
                } else {
                    if (gcol < Nc) {
                        v += bias[gcol];
                        v = 1.f / (1.f + expf(-v));
                        ((float*)Cout)[(size_t)grow * Nc + gcol] = v;
                    }
                }
            }
        }
    }
}

// ------------------------------------------------------------- gate fusion

__global__ void k_gate(const unsigned short* __restrict__ h1, const unsigned short* __restrict__ h2,
                       const float* __restrict__ w1, const float* __restrict__ w1b,
                       const float* __restrict__ w2, const float* __restrict__ w2b,
                       unsigned short* __restrict__ m, int n) {
    int gtid = blockIdx.x * blockDim.x + threadIdx.x;
    int wid = gtid >> 6;
    int lane = threadIdx.x & 63;
    if (wid >= n) return;
    ushort4 av = ((const ushort4*)(h1 + (size_t)wid * HDIM))[lane];
    ushort4 bv = ((const ushort4*)(h2 + (size_t)wid * HDIM))[lane];
    float4 wa = ((const float4*)w1)[lane];
    float4 wb = ((const float4*)w2)[lane];
    float a0 = bf2f(av.x), a1 = bf2f(av.y), a2 = bf2f(av.z), a3 = bf2f(av.w);
    float b0 = bf2f(bv.x), b1 = bf2f(bv.y), b2 = bf2f(bv.z), b3 = bf2f(bv.w);
    float d1 = a0 * wa.x + a1 * wa.y + a2 * wa.z + a3 * wa.w;
    float d2 = b0 * wb.x + b1 * wb.y + b2 * wb.z + b3 * wb.w;
    for (int off = 32; off > 0; off >>= 1) {
        d1 += __shfl_xor(d1, off);
        d2 += __shfl_xor(d2, off);
    }
    float f1 = 1.f / (1.f + expf(-(d1 + w1b[0])));
    float f2 = 1.f / (1.f + expf(-(d2 + w2b[0])));
    float f = f1 / (f1 + f2);
    ushort4 o;
    o.x = f2bf(f * a0 + (1.f - f) * b0);
    o.y = f2bf(f * a1 + (1.f - f) * b1);
    o.z = f2bf(f * a2 + (1.f - f) * b2);
    o.w = f2bf(f * a3 + (1.f - f) * b3);
    ((ushort4*)(m + (size_t)wid * HDIM))[lane] = o;
}

// ------------------------------------------------------------------ launch

extern "C" void kernel_launch(void* const* d_in, const int* in_sizes, int n_in,
                              void* d_out, int out_size, void* d_ws, size_t ws_size,
                              hipStream_t stream) {
    (void)n_in; (void)out_size; (void)ws_size;
    const int N = N_NODES, E = E_EDGES;

    const float* x1; const float* x2; const int* ei1; const int* ei2;
    if (in_sizes[1] == 2 * E) {
        x1 = (const float*)d_in[0]; ei1 = (const int*)d_in[1];
        x2 = (const float*)d_in[2]; ei2 = (const int*)d_in[3];
    } else {
        x1 = (const float*)d_in[0]; x2 = (const float*)d_in[1];
        ei1 = (const int*)d_in[2]; ei2 = (const int*)d_in[3];
    }
    const float* W[2][4]; const float* Bv[2][4];
    int idx = 4;
    for (int br = 0; br < 2; br++)
        for (int l = 0; l < 4; l++) {
            W[br][l] = (const float*)d_in[idx++];
            Bv[br][l] = (const float*)d_in[idx++];
        }
    const float* w1W  = (const float*)d_in[20];
    const float* w1b  = (const float*)d_in[21];
    const float* w2W  = (const float*)d_in[22];
    const float* w2b  = (const float*)d_in[23];
    const float* finW = (const float*)d_in[24];
    const float* finb = (const float*)d_in[25];
    const float* outW = (const float*)d_in[26];
    const float* outb = (const float*)d_in[27];
    float* out = (float*)d_out;

    size_t off = 0;
    auto alloc = [&](size_t bytes) {
        void* p = (char*)d_ws + off;
        off = (off + bytes + 255) & ~(size_t)255;
        return p;
    };
    unsigned short* xb  = (unsigned short*)alloc((size_t)N * F_IN * 2);  // also fin-out t
    unsigned short* gb  = (unsigned short*)alloc((size_t)N * HDIM * 2);  // GEMM out / gate out m
    unsigned short* h1b = (unsigned short*)alloc((size_t)N * HDIM * 2);
    unsigned short* h2b = (unsigned short*)alloc((size_t)N * HDIM * 2);
    unsigned short* Wt[2][4];
    Wt[0][0] = (unsigned short*)alloc((size_t)HDIM * F_IN * 2);
    for (int l = 1; l < 4; l++) Wt[0][l] = (unsigned short*)alloc((size_t)HDIM * HDIM * 2);
    Wt[1][0] = (unsigned short*)alloc((size_t)HDIM * F_IN * 2);
    for (int l = 1; l < 4; l++) Wt[1][l] = (unsigned short*)alloc((size_t)HDIM * HDIM * 2);
    unsigned short* finWt = (unsigned short*)alloc((size_t)HDIM * HDIM * 2);
    unsigned short* outWt = (unsigned short*)alloc((size_t)128 * HDIM * 2);
    int* col    = (int*)alloc((size_t)E * 4);
    float* wgt  = (float*)alloc((size_t)E * 4);
    int* rowptr = (int*)alloc((size_t)(N + 1) * 4);
    int* cnt    = (int*)alloc((size_t)N * 4);
    int* cursor = (int*)alloc((size_t)N * 4);
    float* dinv = (float*)alloc((size_t)N * 4);

    const int BLK = 256;
    int nwaves_grid = (N * 64 + BLK - 1) / BLK;
    int mtiles = (N + 127) / 128;
    dim3 grid_h(HDIM / 128, mtiles);
    dim3 grid_o(1, mtiles);

    hipMemsetAsync(outWt, 0, (size_t)128 * HDIM * 2, stream);
    for (int br = 0; br < 2; br++) {
        k_f2b_t<<<(F_IN * HDIM + 255) / 256, BLK, 0, stream>>>(W[br][0], Wt[br][0], F_IN, HDIM);
        for (int l = 1; l < 4; l++)
            k_f2b_t<<<(HDIM * HDIM + 255) / 256, BLK, 0, stream>>>(W[br][l], Wt[br][l], HDIM, HDIM);
    }
    k_f2b_t<<<(HDIM * HDIM + 255) / 256, BLK, 0, stream>>>(finW, finWt, HDIM, HDIM);
    k_f2b_t<<<(HDIM * L_OUT + 255) / 256, BLK, 0, stream>>>(outW, outWt, HDIM, L_OUT);

    for (int br = 0; br < 2; br++) {
        const int* src = br ? ei2 : ei1;
        const int* dst = src + E;
        const float* x = br ? x2 : x1;
        unsigned short* hb = br ? h2b : h1b;

        hipMemsetAsync(cnt, 0, (size_t)N * 4, stream);
        hipMemsetAsync(cursor, 0, (size_t)N * 4, stream);
        k_count<<<2048, BLK, 0, stream>>>(dst, cnt, E);
        k_scan<<<1, BLK, 0, stream>>>(cnt, rowptr, N);
        k_dinv<<<(N + BLK - 1) / BLK, BLK, 0, stream>>>(cnt, dinv, N);
        k_fill<<<2048, BLK, 0, stream>>>(src, dst, rowptr, cursor, dinv, col, wgt, E);

        k_f2b<<<2048, BLK, 0, stream>>>(x, xb, N * F_IN / 4);

        // layer 1: K=512
        k_gemm<0><<<grid_h, BLK, 0, stream>>>(xb, Wt[br][0], nullptr, gb, N, F_IN, HDIM);
        k_agg<<<nwaves_grid, BLK, 0, stream>>>(gb, rowptr, col, wgt, dinv, Bv[br][0], hb, N, 1);
        // layers 2,3
        for (int l = 1; l <= 2; l++) {
            k_gemm<0><<<grid_h, BLK, 0, stream>>>(hb, Wt[br][l], nullptr, gb, N, HDIM, HDIM);
            k_agg<<<nwaves_grid, BLK, 0, stream>>>(gb, rowptr, col, wgt, dinv, Bv[br][l], hb, N, 1);
        }
        // layer e: no relu
        k_gemm<0><<<grid_h, BLK, 0, stream>>>(hb, Wt[br][3], nullptr, gb, N, HDIM, HDIM);
        k_agg<<<nwaves_grid, BLK, 0, stream>>>(gb, rowptr, col, wgt, dinv, Bv[br][3], hb, N, 0);
    }

    k_gate<<<nwaves_grid, BLK, 0, stream>>>(h1b, h2b, w1W, w1b, w2W, w2b, gb, N);
    k_gemm<1><<<grid_h, BLK, 0, stream>>>(gb, finWt, finb, xb, N, HDIM, HDIM);
    k_gemm<2><<<grid_o, BLK, 0, stream>>>(xb, outWt, outb, out, N, HDIM, L_OUT);
}

// Round 4
// 1615.955 us; speedup vs baseline: 2.2490x; 1.2662x over previous
//
#include <hip/hip_runtime.h>
#include <math.h>

#define N_NODES 50000
#define F_IN    512
#define HDIM    256
#define L_OUT   52
#define E_EDGES 1600000

typedef short short8 __attribute__((ext_vector_type(8)));
typedef float f32x4 __attribute__((ext_vector_type(4)));

__device__ __forceinline__ float bf2f(unsigned short u) {
    unsigned int x = ((unsigned int)u) << 16;
    return __builtin_bit_cast(float, x);
}
__device__ __forceinline__ unsigned short f2bf(float f) {
    unsigned int u = __builtin_bit_cast(unsigned int, f);
    return (unsigned short)((u + 0x7fffu + ((u >> 16) & 1u)) >> 16);
}
__device__ __forceinline__ void gload16(const unsigned short* g, unsigned short* l) {
    __builtin_amdgcn_global_load_lds(
        (const __attribute__((address_space(1))) unsigned int*)(g),
        (__attribute__((address_space(3))) unsigned int*)(l), 16, 0, 0);
}

// ---------------------------------------------------------------- CSR build

__global__ void k_count(const int* __restrict__ dst, int* __restrict__ cnt, int E) {
    int i = blockIdx.x * blockDim.x + threadIdx.x;
    int stride = gridDim.x * blockDim.x;
    for (; i < E; i += stride) atomicAdd(&cnt[dst[i]], 1);
}

__global__ void k_dinv(const int* __restrict__ cnt, float* __restrict__ dinv, int n) {
    int i = blockIdx.x * blockDim.x + threadIdx.x;
    if (i < n) dinv[i] = rsqrtf((float)(cnt[i] + 1));  // +1 self-loop
}

// ---- hierarchical scan: phase 1 (per-chunk inclusive scan + chunk sum)
__global__ void k_scan1(const int* __restrict__ cnt, int* __restrict__ incl,
                        int* __restrict__ bsum, int n) {
    __shared__ int s[256];
    int tid = threadIdx.x;
    int idx = blockIdx.x * 256 + tid;
    int v = (idx < n) ? cnt[idx] : 0;
    s[tid] = v;
    __syncthreads();
#pragma unroll
    for (int off = 1; off < 256; off <<= 1) {
        int t = (tid >= off) ? s[tid - off] : 0;
        __syncthreads();
        s[tid] += t;
        __syncthreads();
    }
    if (idx < n) incl[idx] = s[tid];
    if (tid == 255) bsum[blockIdx.x] = s[255];
}

// ---- phase 2: single block exclusive-scan of chunk sums (nb <= 256), total -> rowptr[n]
__global__ void k_scan2(int* __restrict__ bsum, int* __restrict__ rowptr, int nb, int n) {
    __shared__ int s[256];
    int tid = threadIdx.x;
    int v = (tid < nb) ? bsum[tid] : 0;
    s[tid] = v;
    __syncthreads();
#pragma unroll
    for (int off = 1; off < 256; off <<= 1) {
        int t = (tid >= off) ? s[tid - off] : 0;
        __syncthreads();
        s[tid] += t;
        __syncthreads();
    }
    if (tid < nb) bsum[tid] = s[tid] - v;  // exclusive
    if (tid == nb - 1) rowptr[n] = s[tid];
}

// ---- phase 3: rowptr[i] = incl[i] - cnt[i] + bsum_excl[i>>8]
__global__ void k_scan3(const int* __restrict__ incl, const int* __restrict__ cnt,
                        const int* __restrict__ bsum, int* __restrict__ rowptr, int n) {
    int i = blockIdx.x * blockDim.x + threadIdx.x;
    if (i < n) rowptr[i] = incl[i] - cnt[i] + bsum[i >> 8];
}

// fill CSR cols + per-edge weight wgt = dinv[src]*dinv[dst]
__global__ void k_fill(const int* __restrict__ src, const int* __restrict__ dst,
                       const int* __restrict__ rowptr, int* __restrict__ cursor,
                       const float* __restrict__ dinv,
                       int* __restrict__ col, float* __restrict__ wgt, int E) {
    int i = blockIdx.x * blockDim.x + threadIdx.x;
    int stride = gridDim.x * blockDim.x;
    for (; i < E; i += stride) {
        int s = src[i], d = dst[i];
        int p = atomicAdd(&cursor[d], 1);
        int pos = rowptr[d] + p;
        col[pos] = s;
        wgt[pos] = dinv[s] * dinv[d];
    }
}

// ------------------------------------------------------------- conversions

__global__ void k_f2b(const float* __restrict__ in, unsigned short* __restrict__ out, int n4) {
    int i = blockIdx.x * blockDim.x + threadIdx.x;
    int stride = gridDim.x * blockDim.x;
    for (; i < n4; i += stride) {
        float4 v = ((const float4*)in)[i];
        ushort4 o;
        o.x = f2bf(v.x); o.y = f2bf(v.y); o.z = f2bf(v.z); o.w = f2bf(v.w);
        ((ushort4*)out)[i] = o;
    }
}

// fp32 [K][N] -> bf16 [N][K] (transpose)
__global__ void k_f2b_t(const float* __restrict__ in, unsigned short* __restrict__ out,
                        int K, int N) {
    int idx = blockIdx.x * blockDim.x + threadIdx.x;
    if (idx < K * N) {
        int k = idx / N, n = idx % N;
        out[(size_t)n * K + k] = f2bf(in[idx]);
    }
}

// ---------------------- aggregation (wave/node, bf16, 8-deep MLP unroll)

__global__ void k_agg(const unsigned short* __restrict__ g, const int* __restrict__ rowptr,
                      const int* __restrict__ col, const float* __restrict__ wgt,
                      const float* __restrict__ dinv,
                      const float* __restrict__ bias, unsigned short* __restrict__ out,
                      int n, int do_relu) {
    int gtid = blockIdx.x * blockDim.x + threadIdx.x;
    int wid = gtid >> 6;
    int lane = threadIdx.x & 63;
    if (wid >= n) return;
    float di = dinv[wid];
    ushort4 v0 = ((const ushort4*)(g + (size_t)wid * HDIM))[lane];
    float w0 = di * di;  // self-loop weight
    float a0 = bf2f(v0.x) * w0, a1 = bf2f(v0.y) * w0, a2 = bf2f(v0.z) * w0, a3 = bf2f(v0.w) * w0;
    int r0 = rowptr[wid], r1 = rowptr[wid + 1];

    int e = r0;
    for (; e + 8 <= r1; e += 8) {
        int j[8]; float w[8]; ushort4 v[8];
#pragma unroll
        for (int t = 0; t < 8; t++) { j[t] = col[e + t]; w[t] = wgt[e + t]; }
#pragma unroll
        for (int t = 0; t < 8; t++)
            v[t] = ((const ushort4*)(g + (size_t)j[t] * HDIM))[lane];
#pragma unroll
        for (int t = 0; t < 8; t++) {
            a0 = fmaf(bf2f(v[t].x), w[t], a0);
            a1 = fmaf(bf2f(v[t].y), w[t], a1);
            a2 = fmaf(bf2f(v[t].z), w[t], a2);
            a3 = fmaf(bf2f(v[t].w), w[t], a3);
        }
    }
    {   // remainder, still load-then-use
        int j[8]; float w[8]; ushort4 v[8];
        int m = r1 - e;
#pragma unroll
        for (int t = 0; t < 8; t++) {
            int idx = (t < m) ? e + t : r0;  // dummy safe index
            j[t] = col[idx]; w[t] = (t < m) ? wgt[idx] : 0.f;
        }
#pragma unroll
        for (int t = 0; t < 8; t++)
            v[t] = ((const ushort4*)(g + (size_t)j[t] * HDIM))[lane];
#pragma unroll
        for (int t = 0; t < 8; t++) {
            a0 = fmaf(bf2f(v[t].x), w[t], a0);
            a1 = fmaf(bf2f(v[t].y), w[t], a1);
            a2 = fmaf(bf2f(v[t].z), w[t], a2);
            a3 = fmaf(bf2f(v[t].w), w[t], a3);
        }
    }

    float4 bb = ((const float4*)bias)[lane];
    a0 += bb.x; a1 += bb.y; a2 += bb.z; a3 += bb.w;
    if (do_relu) {
        a0 = fmaxf(a0, 0.f); a1 = fmaxf(a1, 0.f);
        a2 = fmaxf(a2, 0.f); a3 = fmaxf(a3, 0.f);
    }
    ushort4 o;
    o.x = f2bf(a0); o.y = f2bf(a1); o.z = f2bf(a2); o.w = f2bf(a3);
    ((ushort4*)(out + (size_t)wid * HDIM))[lane] = o;
}

// --------------------------------------------------- bf16 MFMA GEMM 128x128

template <int EPI>
__global__ __launch_bounds__(256) void k_gemm(const unsigned short* __restrict__ A,
                                              const unsigned short* __restrict__ Bt,
                                              const float* __restrict__ bias,
                                              void* __restrict__ Cout,
                                              int M, int K, int Nc) {
    __shared__ __align__(16) unsigned short As[128 * 32];
    __shared__ __align__(16) unsigned short Bs[128 * 32];
    int tid = threadIdx.x;
    int wid = tid >> 6, lane = tid & 63;
    int wr = wid >> 1, wc = wid & 1;
    int mb = blockIdx.y * 128, nb = blockIdx.x * 128;

    int sr = tid >> 2;
    int ssl = (tid & 3) ^ ((sr >> 1) & 3);
    int ar0 = mb + sr;      if (ar0 > M - 1) ar0 = M - 1;
    int ar1 = mb + sr + 64; if (ar1 > M - 1) ar1 = M - 1;
    const unsigned short* gA0 = A + (size_t)ar0 * K + ssl * 8;
    const unsigned short* gA1 = A + (size_t)ar1 * K + ssl * 8;
    const unsigned short* gB0 = Bt + (size_t)(nb + sr) * K + ssl * 8;
    const unsigned short* gB1 = Bt + (size_t)(nb + sr + 64) * K + ssl * 8;
    unsigned short* ldsA = As + tid * 8;
    unsigned short* ldsB = Bs + tid * 8;

    f32x4 acc[4][4];
#pragma unroll
    for (int m = 0; m < 4; m++)
#pragma unroll
        for (int n = 0; n < 4; n++) acc[m][n] = (f32x4){0.f, 0.f, 0.f, 0.f};

    int l15 = lane & 15, ks = lane >> 4;

    for (int k0 = 0; k0 < K; k0 += 32) {
        gload16(gA0 + k0, ldsA);
        gload16(gA1 + k0, ldsA + 2048);
        gload16(gB0 + k0, ldsB);
        gload16(gB1 + k0, ldsB + 2048);
        __syncthreads();

        short8 af[4], bfr[4];
#pragma unroll
        for (int m = 0; m < 4; m++) {
            int row = wr * 64 + m * 16 + l15;
            int slot = ks ^ ((row >> 1) & 3);
            af[m] = *(const short8*)((const char*)As + row * 64 + slot * 16);
        }
#pragma unroll
        for (int n = 0; n < 4; n++) {
            int row = wc * 64 + n * 16 + l15;
            int slot = ks ^ ((row >> 1) & 3);
            bfr[n] = *(const short8*)((const char*)Bs + row * 64 + slot * 16);
        }
#pragma unroll
        for (int m = 0; m < 4; m++)
#pragma unroll
            for (int n = 0; n < 4; n++)
                acc[m][n] = __builtin_amdgcn_mfma_f32_16x16x32_bf16(af[m], bfr[n], acc[m][n], 0, 0, 0);
        __syncthreads();
    }

    int lq = lane >> 4;
#pragma unroll
    for (int m = 0; m < 4; m++) {
#pragma unroll
        for (int n = 0; n < 4; n++) {
            int gcol = nb + wc * 64 + n * 16 + l15;
#pragma unroll
            for (int r = 0; r < 4; r++) {
                int grow = mb + wr * 64 + m * 16 + lq * 4 + r;
                if (grow >= M) continue;
                float v = acc[m][n][r];
                if (EPI == 0) {
                    ((unsigned short*)Cout)[(size_t)grow * Nc + gcol] = f2bf(v);
                } else if (EPI == 1) {
                    v += bias[gcol];
                    v = fmaxf(v, 0.f);
                    ((unsigned short*)Cout)[(size_t)grow * Nc + gcol] = f2bf(v);
                } else {
                    if (gcol < Nc) {
                        v += bias[gcol];
                        v = 1.f / (1.f + expf(-v));
                        ((float*)Cout)[(size_t)grow * Nc + gcol] = v;
                    }
                }
            }
        }
    }
}

// ------------------------------------------------------------- gate fusion

__global__ void k_gate(const unsigned short* __restrict__ h1, const unsigned short* __restrict__ h2,
                       const float* __restrict__ w1, const float* __restrict__ w1b,
                       const float* __restrict__ w2, const float* __restrict__ w2b,
                       unsigned short* __restrict__ m, int n) {
    int gtid = blockIdx.x * blockDim.x + threadIdx.x;
    int wid = gtid >> 6;
    int lane = threadIdx.x & 63;
    if (wid >= n) return;
    ushort4 av = ((const ushort4*)(h1 + (size_t)wid * HDIM))[lane];
    ushort4 bv = ((const ushort4*)(h2 + (size_t)wid * HDIM))[lane];
    float4 wa = ((const float4*)w1)[lane];
    float4 wb = ((const float4*)w2)[lane];
    float a0 = bf2f(av.x), a1 = bf2f(av.y), a2 = bf2f(av.z), a3 = bf2f(av.w);
    float b0 = bf2f(bv.x), b1 = bf2f(bv.y), b2 = bf2f(bv.z), b3 = bf2f(bv.w);
    float d1 = a0 * wa.x + a1 * wa.y + a2 * wa.z + a3 * wa.w;
    float d2 = b0 * wb.x + b1 * wb.y + b2 * wb.z + b3 * wb.w;
    for (int off = 32; off > 0; off >>= 1) {
        d1 += __shfl_xor(d1, off);
        d2 += __shfl_xor(d2, off);
    }
    float f1 = 1.f / (1.f + expf(-(d1 + w1b[0])));
    float f2 = 1.f / (1.f + expf(-(d2 + w2b[0])));
    float f = f1 / (f1 + f2);
    ushort4 o;
    o.x = f2bf(f * a0 + (1.f - f) * b0);
    o.y = f2bf(f * a1 + (1.f - f) * b1);
    o.z = f2bf(f * a2 + (1.f - f) * b2);
    o.w = f2bf(f * a3 + (1.f - f) * b3);
    ((ushort4*)(m + (size_t)wid * HDIM))[lane] = o;
}

// ------------------------------------------------------------------ launch

extern "C" void kernel_launch(void* const* d_in, const int* in_sizes, int n_in,
                              void* d_out, int out_size, void* d_ws, size_t ws_size,
                              hipStream_t stream) {
    (void)n_in; (void)out_size; (void)ws_size;
    const int N = N_NODES, E = E_EDGES;

    const float* x1; const float* x2; const int* ei1; const int* ei2;
    if (in_sizes[1] == 2 * E) {
        x1 = (const float*)d_in[0]; ei1 = (const int*)d_in[1];
        x2 = (const float*)d_in[2]; ei2 = (const int*)d_in[3];
    } else {
        x1 = (const float*)d_in[0]; x2 = (const float*)d_in[1];
        ei1 = (const int*)d_in[2]; ei2 = (const int*)d_in[3];
    }
    const float* W[2][4]; const float* Bv[2][4];
    int idx = 4;
    for (int br = 0; br < 2; br++)
        for (int l = 0; l < 4; l++) {
            W[br][l] = (const float*)d_in[idx++];
            Bv[br][l] = (const float*)d_in[idx++];
        }
    const float* w1W  = (const float*)d_in[20];
    const float* w1b  = (const float*)d_in[21];
    const float* w2W  = (const float*)d_in[22];
    const float* w2b  = (const float*)d_in[23];
    const float* finW = (const float*)d_in[24];
    const float* finb = (const float*)d_in[25];
    const float* outW = (const float*)d_in[26];
    const float* outb = (const float*)d_in[27];
    float* out = (float*)d_out;

    size_t off = 0;
    auto alloc = [&](size_t bytes) {
        void* p = (char*)d_ws + off;
        off = (off + bytes + 255) & ~(size_t)255;
        return p;
    };
    unsigned short* xb  = (unsigned short*)alloc((size_t)N * F_IN * 2);  // also fin-out t
    unsigned short* gb  = (unsigned short*)alloc((size_t)N * HDIM * 2);  // GEMM out / gate out m
    unsigned short* h1b = (unsigned short*)alloc((size_t)N * HDIM * 2);
    unsigned short* h2b = (unsigned short*)alloc((size_t)N * HDIM * 2);
    unsigned short* Wt[2][4];
    Wt[0][0] = (unsigned short*)alloc((size_t)HDIM * F_IN * 2);
    for (int l = 1; l < 4; l++) Wt[0][l] = (unsigned short*)alloc((size_t)HDIM * HDIM * 2);
    Wt[1][0] = (unsigned short*)alloc((size_t)HDIM * F_IN * 2);
    for (int l = 1; l < 4; l++) Wt[1][l] = (unsigned short*)alloc((size_t)HDIM * HDIM * 2);
    unsigned short* finWt = (unsigned short*)alloc((size_t)HDIM * HDIM * 2);
    unsigned short* outWt = (unsigned short*)alloc((size_t)128 * HDIM * 2);
    int* col    = (int*)alloc((size_t)E * 4);
    float* wgt  = (float*)alloc((size_t)E * 4);
    int* rowptr = (int*)alloc((size_t)(N + 1) * 4);
    int* incl   = (int*)alloc((size_t)N * 4);
    int* bsum   = (int*)alloc((size_t)256 * 4);
    int* cnt    = (int*)alloc((size_t)N * 4);
    int* cursor = (int*)alloc((size_t)N * 4);
    float* dinv = (float*)alloc((size_t)N * 4);

    const int BLK = 256;
    int nwaves_grid = (N * 64 + BLK - 1) / BLK;
    int nchunks = (N + 255) / 256;   // 196
    int mtiles = (N + 127) / 128;
    dim3 grid_h(HDIM / 128, mtiles);
    dim3 grid_o(1, mtiles);

    hipMemsetAsync(outWt, 0, (size_t)128 * HDIM * 2, stream);
    for (int br = 0; br < 2; br++) {
        k_f2b_t<<<(F_IN * HDIM + 255) / 256, BLK, 0, stream>>>(W[br][0], Wt[br][0], F_IN, HDIM);
        for (int l = 1; l < 4; l++)
            k_f2b_t<<<(HDIM * HDIM + 255) / 256, BLK, 0, stream>>>(W[br][l], Wt[br][l], HDIM, HDIM);
    }
    k_f2b_t<<<(HDIM * HDIM + 255) / 256, BLK, 0, stream>>>(finW, finWt, HDIM, HDIM);
    k_f2b_t<<<(HDIM * L_OUT + 255) / 256, BLK, 0, stream>>>(outW, outWt, HDIM, L_OUT);

    for (int br = 0; br < 2; br++) {
        const int* src = br ? ei2 : ei1;
        const int* dst = src + E;
        const float* x = br ? x2 : x1;
        unsigned short* hb = br ? h2b : h1b;

        hipMemsetAsync(cnt, 0, (size_t)N * 4, stream);
        hipMemsetAsync(cursor, 0, (size_t)N * 4, stream);
        k_count<<<2048, BLK, 0, stream>>>(dst, cnt, E);
        k_scan1<<<nchunks, BLK, 0, stream>>>(cnt, incl, bsum, N);
        k_scan2<<<1, BLK, 0, stream>>>(bsum, rowptr, nchunks, N);
        k_scan3<<<nchunks, BLK, 0, stream>>>(incl, cnt, bsum, rowptr, N);
        k_dinv<<<(N + BLK - 1) / BLK, BLK, 0, stream>>>(cnt, dinv, N);
        k_fill<<<2048, BLK, 0, stream>>>(src, dst, rowptr, cursor, dinv, col, wgt, E);

        k_f2b<<<2048, BLK, 0, stream>>>(x, xb, N * F_IN / 4);

        // layer 1: K=512
        k_gemm<0><<<grid_h, BLK, 0, stream>>>(xb, Wt[br][0], nullptr, gb, N, F_IN, HDIM);
        k_agg<<<nwaves_grid, BLK, 0, stream>>>(gb, rowptr, col, wgt, dinv, Bv[br][0], hb, N, 1);
        // layers 2,3
        for (int l = 1; l <= 2; l++) {
            k_gemm<0><<<grid_h, BLK, 0, stream>>>(hb, Wt[br][l], nullptr, gb, N, HDIM, HDIM);
            k_agg<<<nwaves_grid, BLK, 0, stream>>>(gb, rowptr, col, wgt, dinv, Bv[br][l], hb, N, 1);
        }
        // layer e: no relu
        k_gemm<0><<<grid_h, BLK, 0, stream>>>(hb, Wt[br][3], nullptr, gb, N, HDIM, HDIM);
        k_agg<<<nwaves_grid, BLK, 0, stream>>>(gb, rowptr, col, wgt, dinv, Bv[br][3], hb, N, 0);
    }

    k_gate<<<nwaves_grid, BLK, 0, stream>>>(h1b, h2b, w1W, w1b, w2W, w2b, gb, N);
    k_gemm<1><<<grid_h, BLK, 0, stream>>>(gb, finWt, finb, xb, N, HDIM, HDIM);
    k_gemm<2><<<grid_o, BLK, 0, stream>>>(xb, outWt, outb, out, N, HDIM, L_OUT);
}

// Round 5
// 1527.449 us; speedup vs baseline: 2.3793x; 1.0579x over previous
//
#include <hip/hip_runtime.h>
#include <math.h>

#define N_NODES 50000
#define F_IN    512
#define HDIM    256
#define L_OUT   52
#define E_EDGES 1600000

typedef short short8 __attribute__((ext_vector_type(8)));
typedef unsigned short u16x8 __attribute__((ext_vector_type(8)));
typedef float f32x4 __attribute__((ext_vector_type(4)));

__device__ __forceinline__ float bf2f(unsigned short u) {
    unsigned int x = ((unsigned int)u) << 16;
    return __builtin_bit_cast(float, x);
}
__device__ __forceinline__ unsigned short f2bf(float f) {
    unsigned int u = __builtin_bit_cast(unsigned int, f);
    return (unsigned short)((u + 0x7fffu + ((u >> 16) & 1u)) >> 16);
}
__device__ __forceinline__ void gload16(const unsigned short* g, unsigned short* l) {
    __builtin_amdgcn_global_load_lds(
        (const __attribute__((address_space(1))) unsigned int*)(g),
        (__attribute__((address_space(3))) unsigned int*)(l), 16, 0, 0);
}

// ---------------------------------------------------------------- CSR build

__global__ void k_count(const int* __restrict__ dst, int* __restrict__ cnt, int E) {
    int i = blockIdx.x * blockDim.x + threadIdx.x;
    int stride = gridDim.x * blockDim.x;
    for (; i < E; i += stride) atomicAdd(&cnt[dst[i]], 1);
}

__global__ void k_dinv(const int* __restrict__ cnt, float* __restrict__ dinv, int n) {
    int i = blockIdx.x * blockDim.x + threadIdx.x;
    if (i < n) dinv[i] = rsqrtf((float)(cnt[i] + 1));  // +1 self-loop
}

// ---- hierarchical scan: phase 1 (per-chunk inclusive scan + chunk sum)
__global__ void k_scan1(const int* __restrict__ cnt, int* __restrict__ incl,
                        int* __restrict__ bsum, int n) {
    __shared__ int s[256];
    int tid = threadIdx.x;
    int idx = blockIdx.x * 256 + tid;
    int v = (idx < n) ? cnt[idx] : 0;
    s[tid] = v;
    __syncthreads();
#pragma unroll
    for (int off = 1; off < 256; off <<= 1) {
        int t = (tid >= off) ? s[tid - off] : 0;
        __syncthreads();
        s[tid] += t;
        __syncthreads();
    }
    if (idx < n) incl[idx] = s[tid];
    if (tid == 255) bsum[blockIdx.x] = s[255];
}

// ---- phase 2: single block exclusive-scan of chunk sums (nb <= 256)
__global__ void k_scan2(int* __restrict__ bsum, int* __restrict__ rowptr, int nb, int n) {
    __shared__ int s[256];
    int tid = threadIdx.x;
    int v = (tid < nb) ? bsum[tid] : 0;
    s[tid] = v;
    __syncthreads();
#pragma unroll
    for (int off = 1; off < 256; off <<= 1) {
        int t = (tid >= off) ? s[tid - off] : 0;
        __syncthreads();
        s[tid] += t;
        __syncthreads();
    }
    if (tid < nb) bsum[tid] = s[tid] - v;  // exclusive
    if (tid == nb - 1) rowptr[n] = s[tid];
}

// ---- phase 3: rowptr[i] = incl[i] - cnt[i] + bsum_excl[i>>8]
__global__ void k_scan3(const int* __restrict__ incl, const int* __restrict__ cnt,
                        const int* __restrict__ bsum, int* __restrict__ rowptr, int n) {
    int i = blockIdx.x * blockDim.x + threadIdx.x;
    if (i < n) rowptr[i] = incl[i] - cnt[i] + bsum[i >> 8];
}

// fill CSR: interleaved (col, weight-bits) -> ONE 8B store per edge
__global__ void k_fill(const int* __restrict__ src, const int* __restrict__ dst,
                       const int* __restrict__ rowptr, int* __restrict__ cursor,
                       const float* __restrict__ dinv,
                       int2* __restrict__ cw, int E) {
    int i = blockIdx.x * blockDim.x + threadIdx.x;
    int stride = gridDim.x * blockDim.x;
    for (; i < E; i += stride) {
        int s = src[i], d = dst[i];
        int p = atomicAdd(&cursor[d], 1);
        float w = dinv[s] * dinv[d];
        cw[rowptr[d] + p] = make_int2(s, __builtin_bit_cast(int, w));
    }
}

// ------------------------------------------------------------- conversions

__global__ void k_f2b(const float* __restrict__ in, unsigned short* __restrict__ out, int n4) {
    int i = blockIdx.x * blockDim.x + threadIdx.x;
    int stride = gridDim.x * blockDim.x;
    for (; i < n4; i += stride) {
        float4 v = ((const float4*)in)[i];
        ushort4 o;
        o.x = f2bf(v.x); o.y = f2bf(v.y); o.z = f2bf(v.z); o.w = f2bf(v.w);
        ((ushort4*)out)[i] = o;
    }
}

// fp32 [K][N] -> bf16 [N][K] (transpose)
__global__ void k_f2b_t(const float* __restrict__ in, unsigned short* __restrict__ out,
                        int K, int N) {
    int idx = blockIdx.x * blockDim.x + threadIdx.x;
    if (idx < K * N) {
        int k = idx / N, n = idx % N;
        out[(size_t)n * K + k] = f2bf(in[idx]);
    }
}

// ------- aggregation: wave/node, lane-halves process even/odd neighbors,
//         16B row loads per lane, cross-half shfl reduce.

__global__ void k_agg(const unsigned short* __restrict__ g, const int* __restrict__ rowptr,
                      const int2* __restrict__ cw,
                      const float* __restrict__ dinv,
                      const float* __restrict__ bias, unsigned short* __restrict__ out,
                      int n, int do_relu) {
    int gtid = blockIdx.x * blockDim.x + threadIdx.x;
    int wid = gtid >> 6;
    if (wid >= n) return;
    int lane = threadIdx.x & 63;
    int half = lane >> 5;   // even/odd neighbor stream
    int fl = lane & 31;     // feature group: 8 bf16 = 16B

    float a[8];
#pragma unroll
    for (int k = 0; k < 8; k++) a[k] = 0.f;

    int r0 = rowptr[wid], r1 = rowptr[wid + 1];

    int base = r0;
    for (; base + 16 <= r1; base += 16) {
        int2 c[8]; u16x8 v[8];
#pragma unroll
        for (int t = 0; t < 8; t++) c[t] = cw[base + 2 * t + half];
#pragma unroll
        for (int t = 0; t < 8; t++)
            v[t] = ((const u16x8*)(g + (size_t)c[t].x * HDIM))[fl];
#pragma unroll
        for (int t = 0; t < 8; t++) {
            float w = __builtin_bit_cast(float, c[t].y);
#pragma unroll
            for (int k = 0; k < 8; k++)
                a[k] = fmaf(bf2f(v[t][k]), w, a[k]);
        }
    }
    if (base < r1) {  // remainder 1..15 neighbors, zero-weight padding
        int2 c[8]; u16x8 v[8]; float w[8];
#pragma unroll
        for (int t = 0; t < 8; t++) {
            int idx = base + 2 * t + half;
            int ok = idx < r1;
            c[t] = cw[ok ? idx : r0];
            w[t] = ok ? __builtin_bit_cast(float, c[t].y) : 0.f;
        }
#pragma unroll
        for (int t = 0; t < 8; t++)
            v[t] = ((const u16x8*)(g + (size_t)c[t].x * HDIM))[fl];
#pragma unroll
        for (int t = 0; t < 8; t++)
#pragma unroll
            for (int k = 0; k < 8; k++)
                a[k] = fmaf(bf2f(v[t][k]), w[t], a[k]);
    }

    // combine even/odd partial sums
#pragma unroll
    for (int k = 0; k < 8; k++) a[k] += __shfl_xor(a[k], 32);

    // self-loop + bias + activation (redundant on both halves, store once)
    float di = dinv[wid];
    float w0 = di * di;
    u16x8 sv = ((const u16x8*)(g + (size_t)wid * HDIM))[fl];
    u16x8 o;
#pragma unroll
    for (int k = 0; k < 8; k++) {
        float x = fmaf(bf2f(sv[k]), w0, a[k]) + bias[fl * 8 + k];
        if (do_relu) x = fmaxf(x, 0.f);
        o[k] = f2bf(x);
    }
    if (half == 0)
        ((u16x8*)(out + (size_t)wid * HDIM))[fl] = o;
}

// --------------------------------------------------- bf16 MFMA GEMM 128x128

template <int EPI>
__global__ __launch_bounds__(256) void k_gemm(const unsigned short* __restrict__ A,
                                              const unsigned short* __restrict__ Bt,
                                              const float* __restrict__ bias,
                                              void* __restrict__ Cout,
                                              int M, int K, int Nc) {
    __shared__ __align__(16) unsigned short As[128 * 32];
    __shared__ __align__(16) unsigned short Bs[128 * 32];
    int tid = threadIdx.x;
    int wid = tid >> 6, lane = tid & 63;
    int wr = wid >> 1, wc = wid & 1;
    int mb = blockIdx.y * 128, nb = blockIdx.x * 128;

    int sr = tid >> 2;
    int ssl = (tid & 3) ^ ((sr >> 1) & 3);
    int ar0 = mb + sr;      if (ar0 > M - 1) ar0 = M - 1;
    int ar1 = mb + sr + 64; if (ar1 > M - 1) ar1 = M - 1;
    const unsigned short* gA0 = A + (size_t)ar0 * K + ssl * 8;
    const unsigned short* gA1 = A + (size_t)ar1 * K + ssl * 8;
    const unsigned short* gB0 = Bt + (size_t)(nb + sr) * K + ssl * 8;
    const unsigned short* gB1 = Bt + (size_t)(nb + sr + 64) * K + ssl * 8;
    unsigned short* ldsA = As + tid * 8;
    unsigned short* ldsB = Bs + tid * 8;

    f32x4 acc[4][4];
#pragma unroll
    for (int m = 0; m < 4; m++)
#pragma unroll
        for (int n = 0; n < 4; n++) acc[m][n] = (f32x4){0.f, 0.f, 0.f, 0.f};

    int l15 = lane & 15, ks = lane >> 4;

    for (int k0 = 0; k0 < K; k0 += 32) {
        gload16(gA0 + k0, ldsA);
        gload16(gA1 + k0, ldsA + 2048);
        gload16(gB0 + k0, ldsB);
        gload16(gB1 + k0, ldsB + 2048);
        __syncthreads();

        short8 af[4], bfr[4];
#pragma unroll
        for (int m = 0; m < 4; m++) {
            int row = wr * 64 + m * 16 + l15;
            int slot = ks ^ ((row >> 1) & 3);
            af[m] = *(const short8*)((const char*)As + row * 64 + slot * 16);
        }
#pragma unroll
        for (int n = 0; n < 4; n++) {
            int row = wc * 64 + n * 16 + l15;
            int slot = ks ^ ((row >> 1) & 3);
            bfr[n] = *(const short8*)((const char*)Bs + row * 64 + slot * 16);
        }
#pragma unroll
        for (int m = 0; m < 4; m++)
#pragma unroll
            for (int n = 0; n < 4; n++)
                acc[m][n] = __builtin_amdgcn_mfma_f32_16x16x32_bf16(af[m], bfr[n], acc[m][n], 0, 0, 0);
        __syncthreads();
    }

    int lq = lane >> 4;
#pragma unroll
    for (int m = 0; m < 4; m++) {
#pragma unroll
        for (int n = 0; n < 4; n++) {
            int gcol = nb + wc * 64 + n * 16 + l15;
#pragma unroll
            for (int r = 0; r < 4; r++) {
                int grow = mb + wr * 64 + m * 16 + lq * 4 + r;
                if (grow >= M) continue;
                float v = acc[m][n][r];
                if (EPI == 0) {
                    ((unsigned short*)Cout)[(size_t)grow * Nc + gcol] = f2bf(v);
                } else if (EPI == 1) {
                    v += bias[gcol];
                    v = fmaxf(v, 0.f);
                    ((unsigned short*)Cout)[(size_t)grow * Nc + gcol] = f2bf(v);
                } else {
                    if (gcol < Nc) {
                        v += bias[gcol];
                        v = 1.f / (1.f + expf(-v));
                        ((float*)Cout)[(size_t)grow * Nc + gcol] = v;
                    }
                }
            }
        }
    }
}

// ------------------------------------------------------------- gate fusion

__global__ void k_gate(const unsigned short* __restrict__ h1, const unsigned short* __restrict__ h2,
                       const float* __restrict__ w1, const float* __restrict__ w1b,
                       const float* __restrict__ w2, const float* __restrict__ w2b,
                       unsigned short* __restrict__ m, int n) {
    int gtid = blockIdx.x * blockDim.x + threadIdx.x;
    int wid = gtid >> 6;
    int lane = threadIdx.x & 63;
    if (wid >= n) return;
    ushort4 av = ((const ushort4*)(h1 + (size_t)wid * HDIM))[lane];
    ushort4 bv = ((const ushort4*)(h2 + (size_t)wid * HDIM))[lane];
    float4 wa = ((const float4*)w1)[lane];
    float4 wb = ((const float4*)w2)[lane];
    float a0 = bf2f(av.x), a1 = bf2f(av.y), a2 = bf2f(av.z), a3 = bf2f(av.w);
    float b0 = bf2f(bv.x), b1 = bf2f(bv.y), b2 = bf2f(bv.z), b3 = bf2f(bv.w);
    float d1 = a0 * wa.x + a1 * wa.y + a2 * wa.z + a3 * wa.w;
    float d2 = b0 * wb.x + b1 * wb.y + b2 * wb.z + b3 * wb.w;
    for (int off = 32; off > 0; off >>= 1) {
        d1 += __shfl_xor(d1, off);
        d2 += __shfl_xor(d2, off);
    }
    float f1 = 1.f / (1.f + expf(-(d1 + w1b[0])));
    float f2 = 1.f / (1.f + expf(-(d2 + w2b[0])));
    float f = f1 / (f1 + f2);
    ushort4 o;
    o.x = f2bf(f * a0 + (1.f - f) * b0);
    o.y = f2bf(f * a1 + (1.f - f) * b1);
    o.z = f2bf(f * a2 + (1.f - f) * b2);
    o.w = f2bf(f * a3 + (1.f - f) * b3);
    ((ushort4*)(m + (size_t)wid * HDIM))[lane] = o;
}

// ------------------------------------------------------------------ launch

extern "C" void kernel_launch(void* const* d_in, const int* in_sizes, int n_in,
                              void* d_out, int out_size, void* d_ws, size_t ws_size,
                              hipStream_t stream) {
    (void)n_in; (void)out_size; (void)ws_size;
    const int N = N_NODES, E = E_EDGES;

    const float* x1; const float* x2; const int* ei1; const int* ei2;
    if (in_sizes[1] == 2 * E) {
        x1 = (const float*)d_in[0]; ei1 = (const int*)d_in[1];
        x2 = (const float*)d_in[2]; ei2 = (const int*)d_in[3];
    } else {
        x1 = (const float*)d_in[0]; x2 = (const float*)d_in[1];
        ei1 = (const int*)d_in[2]; ei2 = (const int*)d_in[3];
    }
    const float* W[2][4]; const float* Bv[2][4];
    int idx = 4;
    for (int br = 0; br < 2; br++)
        for (int l = 0; l < 4; l++) {
            W[br][l] = (const float*)d_in[idx++];
            Bv[br][l] = (const float*)d_in[idx++];
        }
    const float* w1W  = (const float*)d_in[20];
    const float* w1b  = (const float*)d_in[21];
    const float* w2W  = (const float*)d_in[22];
    const float* w2b  = (const float*)d_in[23];
    const float* finW = (const float*)d_in[24];
    const float* finb = (const float*)d_in[25];
    const float* outW = (const float*)d_in[26];
    const float* outb = (const float*)d_in[27];
    float* out = (float*)d_out;

    size_t off = 0;
    auto alloc = [&](size_t bytes) {
        void* p = (char*)d_ws + off;
        off = (off + bytes + 255) & ~(size_t)255;
        return p;
    };
    unsigned short* xb  = (unsigned short*)alloc((size_t)N * F_IN * 2);  // also fin-out t
    unsigned short* gb  = (unsigned short*)alloc((size_t)N * HDIM * 2);  // GEMM out / gate out m
    unsigned short* h1b = (unsigned short*)alloc((size_t)N * HDIM * 2);
    unsigned short* h2b = (unsigned short*)alloc((size_t)N * HDIM * 2);
    unsigned short* Wt[2][4];
    Wt[0][0] = (unsigned short*)alloc((size_t)HDIM * F_IN * 2);
    for (int l = 1; l < 4; l++) Wt[0][l] = (unsigned short*)alloc((size_t)HDIM * HDIM * 2);
    Wt[1][0] = (unsigned short*)alloc((size_t)HDIM * F_IN * 2);
    for (int l = 1; l < 4; l++) Wt[1][l] = (unsigned short*)alloc((size_t)HDIM * HDIM * 2);
    unsigned short* finWt = (unsigned short*)alloc((size_t)HDIM * HDIM * 2);
    unsigned short* outWt = (unsigned short*)alloc((size_t)128 * HDIM * 2);
    int2* cw    = (int2*)alloc((size_t)E * 8);
    int* rowptr = (int*)alloc((size_t)(N + 1) * 4);
    int* incl   = (int*)alloc((size_t)N * 4);
    int* bsum   = (int*)alloc((size_t)256 * 4);
    int* cnt    = (int*)alloc((size_t)N * 4);
    int* cursor = (int*)alloc((size_t)N * 4);
    float* dinv = (float*)alloc((size_t)N * 4);

    const int BLK = 256;
    int nwaves_grid = (N * 64 + BLK - 1) / BLK;
    int nchunks = (N + 255) / 256;   // 196
    int mtiles = (N + 127) / 128;
    dim3 grid_h(HDIM / 128, mtiles);
    dim3 grid_o(1, mtiles);

    hipMemsetAsync(outWt, 0, (size_t)128 * HDIM * 2, stream);
    for (int br = 0; br < 2; br++) {
        k_f2b_t<<<(F_IN * HDIM + 255) / 256, BLK, 0, stream>>>(W[br][0], Wt[br][0], F_IN, HDIM);
        for (int l = 1; l < 4; l++)
            k_f2b_t<<<(HDIM * HDIM + 255) / 256, BLK, 0, stream>>>(W[br][l], Wt[br][l], HDIM, HDIM);
    }
    k_f2b_t<<<(HDIM * HDIM + 255) / 256, BLK, 0, stream>>>(finW, finWt, HDIM, HDIM);
    k_f2b_t<<<(HDIM * L_OUT + 255) / 256, BLK, 0, stream>>>(outW, outWt, HDIM, L_OUT);

    for (int br = 0; br < 2; br++) {
        const int* src = br ? ei2 : ei1;
        const int* dst = src + E;
        const float* x = br ? x2 : x1;
        unsigned short* hb = br ? h2b : h1b;

        hipMemsetAsync(cnt, 0, (size_t)N * 4, stream);
        hipMemsetAsync(cursor, 0, (size_t)N * 4, stream);
        k_count<<<2048, BLK, 0, stream>>>(dst, cnt, E);
        k_scan1<<<nchunks, BLK, 0, stream>>>(cnt, incl, bsum, N);
        k_scan2<<<1, BLK, 0, stream>>>(bsum, rowptr, nchunks, N);
        k_scan3<<<nchunks, BLK, 0, stream>>>(incl, cnt, bsum, rowptr, N);
        k_dinv<<<(N + BLK - 1) / BLK, BLK, 0, stream>>>(cnt, dinv, N);
        k_fill<<<2048, BLK, 0, stream>>>(src, dst, rowptr, cursor, dinv, cw, E);

        k_f2b<<<2048, BLK, 0, stream>>>(x, xb, N * F_IN / 4);

        // layer 1: K=512
        k_gemm<0><<<grid_h, BLK, 0, stream>>>(xb, Wt[br][0], nullptr, gb, N, F_IN, HDIM);
        k_agg<<<nwaves_grid, BLK, 0, stream>>>(gb, rowptr, cw, dinv, Bv[br][0], hb, N, 1);
        // layers 2,3
        for (int l = 1; l <= 2; l++) {
            k_gemm<0><<<grid_h, BLK, 0, stream>>>(hb, Wt[br][l], nullptr, gb, N, HDIM, HDIM);
            k_agg<<<nwaves_grid, BLK, 0, stream>>>(gb, rowptr, cw, dinv, Bv[br][l], hb, N, 1);
        }
        // layer e: no relu
        k_gemm<0><<<grid_h, BLK, 0, stream>>>(hb, Wt[br][3], nullptr, gb, N, HDIM, HDIM);
        k_agg<<<nwaves_grid, BLK, 0, stream>>>(gb, rowptr, cw, dinv, Bv[br][3], hb, N, 0);
    }

    k_gate<<<nwaves_grid, BLK, 0, stream>>>(h1b, h2b, w1W, w1b, w2W, w2b, gb, N);
    k_gemm<1><<<grid_h, BLK, 0, stream>>>(gb, finWt, finb, xb, N, HDIM, HDIM);
    k_gemm<2><<<grid_o, BLK, 0, stream>>>(xb, outWt, outb, out, N, HDIM, L_OUT);
}

// Round 6
// 1163.645 us; speedup vs baseline: 3.1231x; 1.3126x over previous
//
#include <hip/hip_runtime.h>
#include <math.h>

#define N_NODES 50000
#define F_IN    512
#define HDIM    256
#define L_OUT   52
#define E_EDGES 1600000

typedef short short8 __attribute__((ext_vector_type(8)));
typedef unsigned short u16x8 __attribute__((ext_vector_type(8)));
typedef float f32x4 __attribute__((ext_vector_type(4)));
typedef float f32x2 __attribute__((ext_vector_type(2)));

__device__ __forceinline__ float bf2f(unsigned short u) {
    unsigned int x = ((unsigned int)u) << 16;
    return __builtin_bit_cast(float, x);
}
__device__ __forceinline__ unsigned short f2bf(float f) {
    unsigned int u = __builtin_bit_cast(unsigned int, f);
    return (unsigned short)((u + 0x7fffu + ((u >> 16) & 1u)) >> 16);
}
__device__ __forceinline__ unsigned char f2fp8(float f) {
    int pk = __builtin_amdgcn_cvt_pk_fp8_f32(f, 0.f, 0, false);
    return (unsigned char)(pk & 0xff);
}
__device__ __forceinline__ void gload16(const unsigned short* g, unsigned short* l) {
    __builtin_amdgcn_global_load_lds(
        (const __attribute__((address_space(1))) unsigned int*)(g),
        (__attribute__((address_space(3))) unsigned int*)(l), 16, 0, 0);
}

// ---------------------------------------------------------------- CSR build

__global__ void k_count(const int* __restrict__ dst, int* __restrict__ cnt, int E) {
    int i = blockIdx.x * blockDim.x + threadIdx.x;
    int stride = gridDim.x * blockDim.x;
    for (; i < E; i += stride) atomicAdd(&cnt[dst[i]], 1);
}

__global__ void k_dinv(const int* __restrict__ cnt, float* __restrict__ dinv, int n) {
    int i = blockIdx.x * blockDim.x + threadIdx.x;
    if (i < n) dinv[i] = rsqrtf((float)(cnt[i] + 1));  // +1 self-loop
}

// ---- hierarchical scan: phase 1 (per-chunk inclusive scan + chunk sum)
__global__ void k_scan1(const int* __restrict__ cnt, int* __restrict__ incl,
                        int* __restrict__ bsum, int n) {
    __shared__ int s[256];
    int tid = threadIdx.x;
    int idx = blockIdx.x * 256 + tid;
    int v = (idx < n) ? cnt[idx] : 0;
    s[tid] = v;
    __syncthreads();
#pragma unroll
    for (int off = 1; off < 256; off <<= 1) {
        int t = (tid >= off) ? s[tid - off] : 0;
        __syncthreads();
        s[tid] += t;
        __syncthreads();
    }
    if (idx < n) incl[idx] = s[tid];
    if (tid == 255) bsum[blockIdx.x] = s[255];
}

// ---- phase 2: single block exclusive-scan of chunk sums (nb <= 256)
__global__ void k_scan2(int* __restrict__ bsum, int* __restrict__ rowptr, int nb, int n) {
    __shared__ int s[256];
    int tid = threadIdx.x;
    int v = (tid < nb) ? bsum[tid] : 0;
    s[tid] = v;
    __syncthreads();
#pragma unroll
    for (int off = 1; off < 256; off <<= 1) {
        int t = (tid >= off) ? s[tid - off] : 0;
        __syncthreads();
        s[tid] += t;
        __syncthreads();
    }
    if (tid < nb) bsum[tid] = s[tid] - v;  // exclusive
    if (tid == nb - 1) rowptr[n] = s[tid];
}

// ---- phase 3: rowptr[i] = incl[i] - cnt[i] + bsum_excl[i>>8]
__global__ void k_scan3(const int* __restrict__ incl, const int* __restrict__ cnt,
                        const int* __restrict__ bsum, int* __restrict__ rowptr, int n) {
    int i = blockIdx.x * blockDim.x + threadIdx.x;
    if (i < n) rowptr[i] = incl[i] - cnt[i] + bsum[i >> 8];
}

// fill CSR: interleaved (col, weight-bits) -> ONE 8B store per edge
__global__ void k_fill(const int* __restrict__ src, const int* __restrict__ dst,
                       const int* __restrict__ rowptr, int* __restrict__ cursor,
                       const float* __restrict__ dinv,
                       int2* __restrict__ cw, int E) {
    int i = blockIdx.x * blockDim.x + threadIdx.x;
    int stride = gridDim.x * blockDim.x;
    for (; i < E; i += stride) {
        int s = src[i], d = dst[i];
        int p = atomicAdd(&cursor[d], 1);
        float w = dinv[s] * dinv[d];
        cw[rowptr[d] + p] = make_int2(s, __builtin_bit_cast(int, w));
    }
}

// ------------------------------------------------------------- conversions

__global__ void k_f2b(const float* __restrict__ in, unsigned short* __restrict__ out, int n4) {
    int i = blockIdx.x * blockDim.x + threadIdx.x;
    int stride = gridDim.x * blockDim.x;
    for (; i < n4; i += stride) {
        float4 v = ((const float4*)in)[i];
        ushort4 o;
        o.x = f2bf(v.x); o.y = f2bf(v.y); o.z = f2bf(v.z); o.w = f2bf(v.w);
        ((ushort4*)out)[i] = o;
    }
}

// fp32 [K][N] -> bf16 [N][K] (transpose)
__global__ void k_f2b_t(const float* __restrict__ in, unsigned short* __restrict__ out,
                        int K, int N) {
    int idx = blockIdx.x * blockDim.x + threadIdx.x;
    if (idx < K * N) {
        int k = idx / N, n = idx % N;
        out[(size_t)n * K + k] = f2bf(in[idx]);
    }
}

// ------- aggregation: wave/node, lane-halves process even/odd neighbors,
//         fp8 rows (256B): each of 32 lanes loads 8B, hw cvt fp8->f32.

__global__ void k_agg(const unsigned char* __restrict__ g, const int* __restrict__ rowptr,
                      const int2* __restrict__ cw,
                      const float* __restrict__ dinv,
                      const float* __restrict__ bias, unsigned short* __restrict__ out,
                      int n, int do_relu) {
    int gtid = blockIdx.x * blockDim.x + threadIdx.x;
    int wid = gtid >> 6;
    if (wid >= n) return;
    int lane = threadIdx.x & 63;
    int half = lane >> 5;   // even/odd neighbor stream
    int fl = lane & 31;     // feature group: 8 fp8 = 8B

    float a[8];
#pragma unroll
    for (int k = 0; k < 8; k++) a[k] = 0.f;

    int r0 = rowptr[wid], r1 = rowptr[wid + 1];

    int base = r0;
    for (; base + 16 <= r1; base += 16) {
        int2 c[8]; uint2 v[8];
#pragma unroll
        for (int t = 0; t < 8; t++) c[t] = cw[base + 2 * t + half];
#pragma unroll
        for (int t = 0; t < 8; t++)
            v[t] = ((const uint2*)(g + (size_t)c[t].x * HDIM))[fl];
#pragma unroll
        for (int t = 0; t < 8; t++) {
            float w = __builtin_bit_cast(float, c[t].y);
            f32x2 p0 = __builtin_amdgcn_cvt_pk_f32_fp8((int)v[t].x, false);
            f32x2 p1 = __builtin_amdgcn_cvt_pk_f32_fp8((int)v[t].x, true);
            f32x2 p2 = __builtin_amdgcn_cvt_pk_f32_fp8((int)v[t].y, false);
            f32x2 p3 = __builtin_amdgcn_cvt_pk_f32_fp8((int)v[t].y, true);
            a[0] = fmaf(p0[0], w, a[0]); a[1] = fmaf(p0[1], w, a[1]);
            a[2] = fmaf(p1[0], w, a[2]); a[3] = fmaf(p1[1], w, a[3]);
            a[4] = fmaf(p2[0], w, a[4]); a[5] = fmaf(p2[1], w, a[5]);
            a[6] = fmaf(p3[0], w, a[6]); a[7] = fmaf(p3[1], w, a[7]);
        }
    }
    if (base < r1) {  // remainder 1..15 neighbors, zero-weight padding
        int2 c[8]; uint2 v[8]; float w[8];
#pragma unroll
        for (int t = 0; t < 8; t++) {
            int idx = base + 2 * t + half;
            int ok = idx < r1;
            c[t] = cw[ok ? idx : r0];
            w[t] = ok ? __builtin_bit_cast(float, c[t].y) : 0.f;
        }
#pragma unroll
        for (int t = 0; t < 8; t++)
            v[t] = ((const uint2*)(g + (size_t)c[t].x * HDIM))[fl];
#pragma unroll
        for (int t = 0; t < 8; t++) {
            f32x2 p0 = __builtin_amdgcn_cvt_pk_f32_fp8((int)v[t].x, false);
            f32x2 p1 = __builtin_amdgcn_cvt_pk_f32_fp8((int)v[t].x, true);
            f32x2 p2 = __builtin_amdgcn_cvt_pk_f32_fp8((int)v[t].y, false);
            f32x2 p3 = __builtin_amdgcn_cvt_pk_f32_fp8((int)v[t].y, true);
            a[0] = fmaf(p0[0], w[t], a[0]); a[1] = fmaf(p0[1], w[t], a[1]);
            a[2] = fmaf(p1[0], w[t], a[2]); a[3] = fmaf(p1[1], w[t], a[3]);
            a[4] = fmaf(p2[0], w[t], a[4]); a[5] = fmaf(p2[1], w[t], a[5]);
            a[6] = fmaf(p3[0], w[t], a[6]); a[7] = fmaf(p3[1], w[t], a[7]);
        }
    }

    // combine even/odd partial sums
#pragma unroll
    for (int k = 0; k < 8; k++) a[k] += __shfl_xor(a[k], 32);

    // self-loop + bias + activation (redundant on both halves, store once)
    float di = dinv[wid];
    float w0 = di * di;
    uint2 sv = ((const uint2*)(g + (size_t)wid * HDIM))[fl];
    f32x2 s0 = __builtin_amdgcn_cvt_pk_f32_fp8((int)sv.x, false);
    f32x2 s1 = __builtin_amdgcn_cvt_pk_f32_fp8((int)sv.x, true);
    f32x2 s2 = __builtin_amdgcn_cvt_pk_f32_fp8((int)sv.y, false);
    f32x2 s3 = __builtin_amdgcn_cvt_pk_f32_fp8((int)sv.y, true);
    float sf[8] = {s0[0], s0[1], s1[0], s1[1], s2[0], s2[1], s3[0], s3[1]};
    u16x8 o;
#pragma unroll
    for (int k = 0; k < 8; k++) {
        float x = fmaf(sf[k], w0, a[k]) + bias[fl * 8 + k];
        if (do_relu) x = fmaxf(x, 0.f);
        o[k] = f2bf(x);
    }
    if (half == 0)
        ((u16x8*)(out + (size_t)wid * HDIM))[fl] = o;
}

// --------------------------------------------------- bf16 MFMA GEMM 128x128
// EPI 0: raw -> fp8 C (stride Nc).  EPI 1: bias+relu -> bf16.
// EPI 2: bias+sigmoid -> fp32, col<Nc guard.

template <int EPI>
__global__ __launch_bounds__(256) void k_gemm(const unsigned short* __restrict__ A,
                                              const unsigned short* __restrict__ Bt,
                                              const float* __restrict__ bias,
                                              void* __restrict__ Cout,
                                              int M, int K, int Nc) {
    __shared__ __align__(16) unsigned short As[128 * 32];
    __shared__ __align__(16) unsigned short Bs[128 * 32];
    int tid = threadIdx.x;
    int wid = tid >> 6, lane = tid & 63;
    int wr = wid >> 1, wc = wid & 1;
    int mb = blockIdx.y * 128, nb = blockIdx.x * 128;

    int sr = tid >> 2;
    int ssl = (tid & 3) ^ ((sr >> 1) & 3);
    int ar0 = mb + sr;      if (ar0 > M - 1) ar0 = M - 1;
    int ar1 = mb + sr + 64; if (ar1 > M - 1) ar1 = M - 1;
    const unsigned short* gA0 = A + (size_t)ar0 * K + ssl * 8;
    const unsigned short* gA1 = A + (size_t)ar1 * K + ssl * 8;
    const unsigned short* gB0 = Bt + (size_t)(nb + sr) * K + ssl * 8;
    const unsigned short* gB1 = Bt + (size_t)(nb + sr + 64) * K + ssl * 8;
    unsigned short* ldsA = As + tid * 8;
    unsigned short* ldsB = Bs + tid * 8;

    f32x4 acc[4][4];
#pragma unroll
    for (int m = 0; m < 4; m++)
#pragma unroll
        for (int n = 0; n < 4; n++) acc[m][n] = (f32x4){0.f, 0.f, 0.f, 0.f};

    int l15 = lane & 15, ks = lane >> 4;

    for (int k0 = 0; k0 < K; k0 += 32) {
        gload16(gA0 + k0, ldsA);
        gload16(gA1 + k0, ldsA + 2048);
        gload16(gB0 + k0, ldsB);
        gload16(gB1 + k0, ldsB + 2048);
        __syncthreads();

        short8 af[4], bfr[4];
#pragma unroll
        for (int m = 0; m < 4; m++) {
            int row = wr * 64 + m * 16 + l15;
            int slot = ks ^ ((row >> 1) & 3);
            af[m] = *(const short8*)((const char*)As + row * 64 + slot * 16);
        }
#pragma unroll
        for (int n = 0; n < 4; n++) {
            int row = wc * 64 + n * 16 + l15;
            int slot = ks ^ ((row >> 1) & 3);
            bfr[n] = *(const short8*)((const char*)Bs + row * 64 + slot * 16);
        }
#pragma unroll
        for (int m = 0; m < 4; m++)
#pragma unroll
            for (int n = 0; n < 4; n++)
                acc[m][n] = __builtin_amdgcn_mfma_f32_16x16x32_bf16(af[m], bfr[n], acc[m][n], 0, 0, 0);
        __syncthreads();
    }

    int lq = lane >> 4;
#pragma unroll
    for (int m = 0; m < 4; m++) {
#pragma unroll
        for (int n = 0; n < 4; n++) {
            int gcol = nb + wc * 64 + n * 16 + l15;
#pragma unroll
            for (int r = 0; r < 4; r++) {
                int grow = mb + wr * 64 + m * 16 + lq * 4 + r;
                if (grow >= M) continue;
                float v = acc[m][n][r];
                if (EPI == 0) {
                    ((unsigned char*)Cout)[(size_t)grow * Nc + gcol] = f2fp8(v);
                } else if (EPI == 1) {
                    v += bias[gcol];
                    v = fmaxf(v, 0.f);
                    ((unsigned short*)Cout)[(size_t)grow * Nc + gcol] = f2bf(v);
                } else {
                    if (gcol < Nc) {
                        v += bias[gcol];
                        v = 1.f / (1.f + expf(-v));
                        ((float*)Cout)[(size_t)grow * Nc + gcol] = v;
                    }
                }
            }
        }
    }
}

// ------------------------------------------------------------- gate fusion

__global__ void k_gate(const unsigned short* __restrict__ h1, const unsigned short* __restrict__ h2,
                       const float* __restrict__ w1, const float* __restrict__ w1b,
                       const float* __restrict__ w2, const float* __restrict__ w2b,
                       unsigned short* __restrict__ m, int n) {
    int gtid = blockIdx.x * blockDim.x + threadIdx.x;
    int wid = gtid >> 6;
    int lane = threadIdx.x & 63;
    if (wid >= n) return;
    ushort4 av = ((const ushort4*)(h1 + (size_t)wid * HDIM))[lane];
    ushort4 bv = ((const ushort4*)(h2 + (size_t)wid * HDIM))[lane];
    float4 wa = ((const float4*)w1)[lane];
    float4 wb = ((const float4*)w2)[lane];
    float a0 = bf2f(av.x), a1 = bf2f(av.y), a2 = bf2f(av.z), a3 = bf2f(av.w);
    float b0 = bf2f(bv.x), b1 = bf2f(bv.y), b2 = bf2f(bv.z), b3 = bf2f(bv.w);
    float d1 = a0 * wa.x + a1 * wa.y + a2 * wa.z + a3 * wa.w;
    float d2 = b0 * wb.x + b1 * wb.y + b2 * wb.z + b3 * wb.w;
    for (int off = 32; off > 0; off >>= 1) {
        d1 += __shfl_xor(d1, off);
        d2 += __shfl_xor(d2, off);
    }
    float f1 = 1.f / (1.f + expf(-(d1 + w1b[0])));
    float f2 = 1.f / (1.f + expf(-(d2 + w2b[0])));
    float f = f1 / (f1 + f2);
    ushort4 o;
    o.x = f2bf(f * a0 + (1.f - f) * b0);
    o.y = f2bf(f * a1 + (1.f - f) * b1);
    o.z = f2bf(f * a2 + (1.f - f) * b2);
    o.w = f2bf(f * a3 + (1.f - f) * b3);
    ((ushort4*)(m + (size_t)wid * HDIM))[lane] = o;
}

// ------------------------------------------------------------------ launch

extern "C" void kernel_launch(void* const* d_in, const int* in_sizes, int n_in,
                              void* d_out, int out_size, void* d_ws, size_t ws_size,
                              hipStream_t stream) {
    (void)n_in; (void)out_size; (void)ws_size;
    const int N = N_NODES, E = E_EDGES;

    const float* x1; const float* x2; const int* ei1; const int* ei2;
    if (in_sizes[1] == 2 * E) {
        x1 = (const float*)d_in[0]; ei1 = (const int*)d_in[1];
        x2 = (const float*)d_in[2]; ei2 = (const int*)d_in[3];
    } else {
        x1 = (const float*)d_in[0]; x2 = (const float*)d_in[1];
        ei1 = (const int*)d_in[2]; ei2 = (const int*)d_in[3];
    }
    const float* W[2][4]; const float* Bv[2][4];
    int idx = 4;
    for (int br = 0; br < 2; br++)
        for (int l = 0; l < 4; l++) {
            W[br][l] = (const float*)d_in[idx++];
            Bv[br][l] = (const float*)d_in[idx++];
        }
    const float* w1W  = (const float*)d_in[20];
    const float* w1b  = (const float*)d_in[21];
    const float* w2W  = (const float*)d_in[22];
    const float* w2b  = (const float*)d_in[23];
    const float* finW = (const float*)d_in[24];
    const float* finb = (const float*)d_in[25];
    const float* outW = (const float*)d_in[26];
    const float* outb = (const float*)d_in[27];
    float* out = (float*)d_out;

    size_t off = 0;
    auto alloc = [&](size_t bytes) {
        void* p = (char*)d_ws + off;
        off = (off + bytes + 255) & ~(size_t)255;
        return p;
    };
    unsigned short* xb  = (unsigned short*)alloc((size_t)N * F_IN * 2);  // also fin-out t
    unsigned char*  g8  = (unsigned char*)alloc((size_t)N * HDIM);       // fp8 GEMM out (gathered)
    unsigned short* mb_ = (unsigned short*)alloc((size_t)N * HDIM * 2);  // gate out m (bf16)
    unsigned short* h1b = (unsigned short*)alloc((size_t)N * HDIM * 2);
    unsigned short* h2b = (unsigned short*)alloc((size_t)N * HDIM * 2);
    unsigned short* Wt[2][4];
    Wt[0][0] = (unsigned short*)alloc((size_t)HDIM * F_IN * 2);
    for (int l = 1; l < 4; l++) Wt[0][l] = (unsigned short*)alloc((size_t)HDIM * HDIM * 2);
    Wt[1][0] = (unsigned short*)alloc((size_t)HDIM * F_IN * 2);
    for (int l = 1; l < 4; l++) Wt[1][l] = (unsigned short*)alloc((size_t)HDIM * HDIM * 2);
    unsigned short* finWt = (unsigned short*)alloc((size_t)HDIM * HDIM * 2);
    unsigned short* outWt = (unsigned short*)alloc((size_t)128 * HDIM * 2);
    int2* cw    = (int2*)alloc((size_t)E * 8);
    int* rowptr = (int*)alloc((size_t)(N + 1) * 4);
    int* incl   = (int*)alloc((size_t)N * 4);
    int* bsum   = (int*)alloc((size_t)256 * 4);
    int* cnt    = (int*)alloc((size_t)N * 4);
    int* cursor = (int*)alloc((size_t)N * 4);
    float* dinv = (float*)alloc((size_t)N * 4);

    const int BLK = 256;
    int nwaves_grid = (N * 64 + BLK - 1) / BLK;
    int nchunks = (N + 255) / 256;   // 196
    int mtiles = (N + 127) / 128;
    dim3 grid_h(HDIM / 128, mtiles);
    dim3 grid_o(1, mtiles);

    hipMemsetAsync(outWt, 0, (size_t)128 * HDIM * 2, stream);
    for (int br = 0; br < 2; br++) {
        k_f2b_t<<<(F_IN * HDIM + 255) / 256, BLK, 0, stream>>>(W[br][0], Wt[br][0], F_IN, HDIM);
        for (int l = 1; l < 4; l++)
            k_f2b_t<<<(HDIM * HDIM + 255) / 256, BLK, 0, stream>>>(W[br][l], Wt[br][l], HDIM, HDIM);
    }
    k_f2b_t<<<(HDIM * HDIM + 255) / 256, BLK, 0, stream>>>(finW, finWt, HDIM, HDIM);
    k_f2b_t<<<(HDIM * L_OUT + 255) / 256, BLK, 0, stream>>>(outW, outWt, HDIM, L_OUT);

    for (int br = 0; br < 2; br++) {
        const int* src = br ? ei2 : ei1;
        const int* dst = src + E;
        const float* x = br ? x2 : x1;
        unsigned short* hb = br ? h2b : h1b;

        hipMemsetAsync(cnt, 0, (size_t)N * 4, stream);
        hipMemsetAsync(cursor, 0, (size_t)N * 4, stream);
        k_count<<<2048, BLK, 0, stream>>>(dst, cnt, E);
        k_scan1<<<nchunks, BLK, 0, stream>>>(cnt, incl, bsum, N);
        k_scan2<<<1, BLK, 0, stream>>>(bsum, rowptr, nchunks, N);
        k_scan3<<<nchunks, BLK, 0, stream>>>(incl, cnt, bsum, rowptr, N);
        k_dinv<<<(N + BLK - 1) / BLK, BLK, 0, stream>>>(cnt, dinv, N);
        k_fill<<<2048, BLK, 0, stream>>>(src, dst, rowptr, cursor, dinv, cw, E);

        k_f2b<<<2048, BLK, 0, stream>>>(x, xb, N * F_IN / 4);

        // layer 1: K=512
        k_gemm<0><<<grid_h, BLK, 0, stream>>>(xb, Wt[br][0], nullptr, g8, N, F_IN, HDIM);
        k_agg<<<nwaves_grid, BLK, 0, stream>>>(g8, rowptr, cw, dinv, Bv[br][0], hb, N, 1);
        // layers 2,3
        for (int l = 1; l <= 2; l++) {
            k_gemm<0><<<grid_h, BLK, 0, stream>>>(hb, Wt[br][l], nullptr, g8, N, HDIM, HDIM);
            k_agg<<<nwaves_grid, BLK, 0, stream>>>(g8, rowptr, cw, dinv, Bv[br][l], hb, N, 1);
        }
        // layer e: no relu
        k_gemm<0><<<grid_h, BLK, 0, stream>>>(hb, Wt[br][3], nullptr, g8, N, HDIM, HDIM);
        k_agg<<<nwaves_grid, BLK, 0, stream>>>(g8, rowptr, cw, dinv, Bv[br][3], hb, N, 0);
    }

    k_gate<<<nwaves_grid, BLK, 0, stream>>>(h1b, h2b, w1W, w1b, w2W, w2b, mb_, N);
    k_gemm<1><<<grid_h, BLK, 0, stream>>>(mb_, finWt, finb, xb, N, HDIM, HDIM);
    k_gemm<2><<<grid_o, BLK, 0, stream>>>(xb, outWt, outb, out, N, HDIM, L_OUT);
}